// Round 16
// baseline (106.036 us; speedup 1.0000x reference)
//
#include <hip/hip_runtime.h>

typedef __bf16 bf16x8 __attribute__((ext_vector_type(8)));
typedef __bf16 bf16x4 __attribute__((ext_vector_type(4)));
typedef float  f32x4  __attribute__((ext_vector_type(4)));
typedef unsigned long long u64;

constexpr int PAD       = 64;    // padded CSR row stride
constexpr int BIN_SHIFT = 7;     // 128 nodes / bin -> 391 bins (bin == csr_build block)
constexpr int NBMAX     = 512;   // hist/scan array size (>= 391)
constexpr int CAP       = 3072;  // u64 slots per bin (mean 2046, +22 sigma)
constexpr int NPS       = 128;   // nodes per csr_build block (== bin size)
constexpr int STR       = 68;    // csr_build LDS row stride (ints)
constexpr int CUR_STR   = 16;    // bincur: one 64B line per bin
constexpr int EPB       = 2048;  // edges per fill block

// ---------------- init: zero bin cursors + sentinel zero-rows ----------------

__global__ void init_k(int* __restrict__ bincur, __bf16* __restrict__ h1zero,
                       __bf16* __restrict__ h3zero) {
  int t = threadIdx.x;
  for (int i = t; i < NBMAX * CUR_STR; i += 256) bincur[i] = 0;
  if (t < 128) h1zero[t] = (__bf16)0.f;
  if (t < 64)  h3zero[t] = (__bf16)0.f;
}

// ---------------- kernel 2: role-split {binning fill || GEMM1} ----------------
// Blocks [0, fillB): LDS counting-sort of a 2048-edge slice into 128-node bins,
// reserve per-bin space via line-padded global atomics, flush sorted runs.
// Blocks [fillB, fillB+gemmB): h1b = bf16(x @ W1), grid-stride M-tiles.
// All 519 blocks co-resident (34.8KB LDS -> 4/CU); GEMM hides under fill.

__global__ __launch_bounds__(256) void fused_bin_gemm_k(
    const int* __restrict__ src, const int* __restrict__ dst,
    int* __restrict__ bincur, u64* __restrict__ bin_data, int E, int fillB,
    const float* __restrict__ X, const float* __restrict__ W,
    __bf16* __restrict__ C, int n) {
  constexpr int K = 128, KP = 136, NC = 128, NT = 8, KC = 4;

  __shared__ __align__(16) char smem[NC * KP * 2];  // 34816 B

  const int t = threadIdx.x;

  if ((int)blockIdx.x < fillB) {
    u64* pairs = (u64*)smem;                 // 16384
    int* binof = (int*)(smem + 16384);       // 8192
    int* hist  = (int*)(smem + 24576);       // 2048
    int* cur   = (int*)(smem + 26624);       // 2048
    int* sbase = (int*)(smem + 28672);       // 2048
    int* gbase = (int*)(smem + 30720);       // 2048
    int* p     = (int*)(smem + 32768);       // 1024 -> 33792 <= 34816
    const int NB = (n + ((1 << BIN_SHIFT) - 1)) >> BIN_SHIFT;  // 391

    for (int i = t; i < NBMAX; i += 256) { hist[i] = 0; cur[i] = 0; }
    __syncthreads();

    int base_e = blockIdx.x * EPB + t * 8;
    int m = E - base_e;
    m = m < 0 ? 0 : (m > 8 ? 8 : m);

    int sa[8], da[8], ba[8];
    if (m == 8) {
      int4 s0 = *reinterpret_cast<const int4*>(src + base_e);
      int4 s1 = *reinterpret_cast<const int4*>(src + base_e + 4);
      int4 d0 = *reinterpret_cast<const int4*>(dst + base_e);
      int4 d1 = *reinterpret_cast<const int4*>(dst + base_e + 4);
      sa[0]=s0.x; sa[1]=s0.y; sa[2]=s0.z; sa[3]=s0.w;
      sa[4]=s1.x; sa[5]=s1.y; sa[6]=s1.z; sa[7]=s1.w;
      da[0]=d0.x; da[1]=d0.y; da[2]=d0.z; da[3]=d0.w;
      da[4]=d1.x; da[5]=d1.y; da[6]=d1.z; da[7]=d1.w;
    } else {
      for (int k = 0; k < m; ++k) { sa[k] = src[base_e + k]; da[k] = dst[base_e + k]; }
    }
    for (int k = 0; k < m; ++k) {
      ba[k] = da[k] >> BIN_SHIFT;
      atomicAdd(&hist[ba[k]], 1);
    }
    __syncthreads();

    // 2-level exclusive scan of hist[0..511] -> sbase
    p[t] = hist[2 * t] + hist[2 * t + 1];
    __syncthreads();
    for (int off = 1; off < 256; off <<= 1) {
      int u = (t >= off) ? p[t - off] : 0;
      __syncthreads();
      p[t] += u;
      __syncthreads();
    }
    {
      int ex = (t == 0) ? 0 : p[t - 1];
      sbase[2 * t]     = ex;
      sbase[2 * t + 1] = ex + hist[2 * t];
    }
    for (int b = t; b < NBMAX; b += 256)
      if (b < NB && hist[b] > 0)
        gbase[b] = atomicAdd(&bincur[b * CUR_STR], hist[b]);
    __syncthreads();

    for (int k = 0; k < m; ++k) {
      int b = ba[k];
      int q = atomicAdd(&cur[b], 1);
      int slot = sbase[b] + q;
      pairs[slot] = ((u64)(unsigned)sa[k] << 32) | (unsigned)da[k];
      binof[slot] = b;
    }
    __syncthreads();

    int T = E - blockIdx.x * EPB;
    T = T > EPB ? EPB : T;
    for (int i = t; i < T; i += 256) {
      int b = binof[i];
      int pos = gbase[b] + (i - sbase[b]);
      if (pos < CAP) bin_data[(size_t)b * CAP + pos] = pairs[i];
    }
    return;
  }

  // ---- GEMM1: h1b = bf16(x @ W1) ----
  __bf16* WT = (__bf16*)smem;
  for (int idx = t; idx < K * NC / 4; idx += 256) {
    int col = idx & 127;
    int k4  = idx >> 7;
    bf16x4 w;
    w[0] = (__bf16)W[(k4 * 4 + 0) * NC + col];
    w[1] = (__bf16)W[(k4 * 4 + 1) * NC + col];
    w[2] = (__bf16)W[(k4 * 4 + 2) * NC + col];
    w[3] = (__bf16)W[(k4 * 4 + 3) * NC + col];
    *reinterpret_cast<bf16x4*>(&WT[col * KP + k4 * 4]) = w;
  }
  __syncthreads();

  const int lane = t & 63;
  const int lr = lane & 15;
  const int lg = lane >> 4;

  bf16x8 bfrag[NT][KC];
#pragma unroll
  for (int nt = 0; nt < NT; ++nt)
#pragma unroll
    for (int kc = 0; kc < KC; ++kc)
      bfrag[nt][kc] = *reinterpret_cast<const bf16x8*>(
          &WT[(nt * 16 + lr) * KP + kc * 32 + lg * 8]);

  const int gw = (blockIdx.x - fillB) * 4 + (t >> 6);
  const int nw = (gridDim.x - fillB) * 4;
  const int mtiles = (n + 15) / 16;

  for (int mt = gw; mt < mtiles; mt += nw) {
    const int row  = mt * 16 + lr;
    const int crow = (row < n) ? row : (n - 1);

    bf16x8 afrag[KC];
#pragma unroll
    for (int kc = 0; kc < KC; ++kc) {
      const f32x4* p4 = reinterpret_cast<const f32x4*>(
          X + (size_t)crow * K + kc * 32 + lg * 8);
      f32x4 v0 = p4[0], v1 = p4[1];
      bf16x8 a;
      a[0] = (__bf16)v0[0]; a[1] = (__bf16)v0[1];
      a[2] = (__bf16)v0[2]; a[3] = (__bf16)v0[3];
      a[4] = (__bf16)v1[0]; a[5] = (__bf16)v1[1];
      a[6] = (__bf16)v1[2]; a[7] = (__bf16)v1[3];
      afrag[kc] = a;
    }

    f32x4 acc[NT];
#pragma unroll
    for (int nt = 0; nt < NT; ++nt) acc[nt] = (f32x4){0.f, 0.f, 0.f, 0.f};
#pragma unroll
    for (int kc = 0; kc < KC; ++kc)
#pragma unroll
      for (int nt = 0; nt < NT; ++nt)
        acc[nt] = __builtin_amdgcn_mfma_f32_16x16x32_bf16(afrag[kc], bfrag[nt][kc],
                                                          acc[nt], 0, 0, 0);

#pragma unroll
    for (int nt = 0; nt < NT; ++nt)
#pragma unroll
      for (int r = 0; r < 4; ++r) {
        int orow = mt * 16 + lg * 4 + r;
        if (orow < n) C[(size_t)orow * NC + nt * 16 + lr] = (__bf16)acc[nt][r];
      }
  }
}

// ---------------- kernel 3: bin -> padded CSR + cnt/dinv + h1b*=dinv ----------------
// block == bin (128 nodes): reads its ~2k edges exactly once (no SUBS
// redundancy), LDS-scatters, writes coalesced rows + cnt/dinv + prescale.

__global__ __launch_bounds__(512) void csr_build_k(const int* __restrict__ bincur,
                                                   const u64* __restrict__ bin_data,
                                                   int* __restrict__ srcs_pad,
                                                   int* __restrict__ cnt,
                                                   float* __restrict__ dinv,
                                                   __bf16* __restrict__ h1b, int n) {
  __shared__ int rows[NPS * STR];   // 34816 B
  __shared__ int lcnt[NPS];

  const int bin = blockIdx.x;
  const int lo  = bin << BIN_SHIFT;
  const int hi  = min(n, lo + NPS);

  for (int i = threadIdx.x; i < NPS * STR; i += 512) rows[i] = n;  // sentinel
  for (int i = threadIdx.x; i < NPS; i += 512) lcnt[i] = 0;
  __syncthreads();

  int cntE = bincur[bin * CUR_STR];
  cntE = cntE < CAP ? cntE : CAP;
  const u64* bd = bin_data + (size_t)bin * CAP;

  for (int i = threadIdx.x; i < cntE; i += 512) {
    u64 p = bd[i];
    int d = (int)(p & 0xffffffffu);
    unsigned l = (unsigned)(d - lo);
    if (l < (unsigned)NPS) {
      int q = atomicAdd(&lcnt[l], 1);
      if (q < PAD) rows[l * STR + q] = (int)(p >> 32);
    }
  }
  __syncthreads();

  for (int i = threadIdx.x; i < NPS * (PAD / 4); i += 512) {
    int nl = i >> 4;
    int c4 = i & 15;
    int g = lo + nl;
    if (g < hi)
      *reinterpret_cast<int4*>(&srcs_pad[(size_t)g * PAD + c4 * 4]) =
          *reinterpret_cast<const int4*>(&rows[nl * STR + c4 * 4]);
  }
  for (int i = threadIdx.x; i < NPS; i += 512) {
    int g = lo + i;
    if (g < hi) {
      int c = lcnt[i];
      cnt[g] = c;
      dinv[g] = rsqrtf((float)(c + 1));
    }
  }
  bf16x8* h8 = reinterpret_cast<bf16x8*>(h1b);
  for (int i = threadIdx.x; i < NPS * 16; i += 512) {
    int nl = i >> 4;
    int c8 = i & 15;
    int g = lo + nl;
    if (g < hi) {
      float di = rsqrtf((float)(lcnt[nl] + 1));
      bf16x8 v = h8[(size_t)g * 16 + c8];
      bf16x8 o;
#pragma unroll
      for (int q = 0; q < 8; ++q) o[q] = (__bf16)((float)v[q] * di);
      h8[(size_t)g * 16 + c8] = o;
    }
  }
}

// ---------------- kernel 4: fused {gather1 -> LDS -> GEMM2 -> scaled h3b} ----------------

__global__ __launch_bounds__(256) void gather_gemm2_k(
    const __bf16* __restrict__ h1b, const int* __restrict__ cnt,
    const int* __restrict__ srcs_pad, const float* __restrict__ dinv,
    const float* __restrict__ b1, const float* __restrict__ W2,
    __bf16* __restrict__ h3b, int n) {
  constexpr int K  = 128;
  constexpr int KP = 136;
  constexpr int NT = 4;
  constexpr int KC = 4;

  __shared__ __bf16 W2T[64 * KP];   // 17408 B
  __shared__ __bf16 aggT[64 * KP];  // 17408 B

  const int t = threadIdx.x;

  for (int idx = t; idx < K * 64 / 4; idx += 256) {
    int col = idx & 63;
    int k4  = idx >> 6;
    bf16x4 w;
    w[0] = (__bf16)W2[(k4 * 4 + 0) * 64 + col];
    w[1] = (__bf16)W2[(k4 * 4 + 1) * 64 + col];
    w[2] = (__bf16)W2[(k4 * 4 + 2) * 64 + col];
    w[3] = (__bf16)W2[(k4 * 4 + 3) * 64 + col];
    *reinterpret_cast<bf16x4*>(&W2T[col * KP + k4 * 4]) = w;
  }

  const int base = blockIdx.x * 64;
  const bf16x8* h8 = reinterpret_cast<const bf16x8*>(h1b);
#pragma unroll
  for (int pass = 0; pass < 4; ++pass) {
    const int nl = pass * 16 + (t >> 4);
    const int d8 = t & 15;
    const int node = base + nl;
    bf16x8 ov;
    if (node < n) {
      int c = cnt[node];
      c = c < PAD ? c : PAD;
      const float di = dinv[node];
      const int* row = srcs_pad + (size_t)node * PAD;
      bf16x8 sv = h8[(size_t)node * 16 + d8];

      float acc[8];
#pragma unroll
      for (int q = 0; q < 8; ++q) acc[q] = 0.f;

      for (int j0 = 0; j0 < c; j0 += 8) {
        int4 a = *reinterpret_cast<const int4*>(row + j0);
        int4 b = *reinterpret_cast<const int4*>(row + j0 + 4);
        bf16x8 v0 = h8[(size_t)a.x * 16 + d8];
        bf16x8 v1 = h8[(size_t)a.y * 16 + d8];
        bf16x8 v2 = h8[(size_t)a.z * 16 + d8];
        bf16x8 v3 = h8[(size_t)a.w * 16 + d8];
        bf16x8 v4 = h8[(size_t)b.x * 16 + d8];
        bf16x8 v5 = h8[(size_t)b.y * 16 + d8];
        bf16x8 v6 = h8[(size_t)b.z * 16 + d8];
        bf16x8 v7 = h8[(size_t)b.w * 16 + d8];
#pragma unroll
        for (int q = 0; q < 8; ++q)
          acc[q] += ((float)v0[q] + (float)v1[q]) + ((float)v2[q] + (float)v3[q]) +
                    ((float)v4[q] + (float)v5[q]) + ((float)v6[q] + (float)v7[q]);
      }
#pragma unroll
      for (int q = 0; q < 8; ++q) {
        float val = (acc[q] + (float)sv[q]) * di + b1[d8 * 8 + q];
        ov[q] = (__bf16)fmaxf(val, 0.f);
      }
    } else {
#pragma unroll
      for (int q = 0; q < 8; ++q) ov[q] = (__bf16)0.f;
    }
    *reinterpret_cast<bf16x8*>(&aggT[nl * KP + d8 * 8]) = ov;
  }
  __syncthreads();

  const int lane = t & 63;
  const int lr = lane & 15;
  const int lg = lane >> 4;
  const int wv = t >> 6;

  bf16x8 bfrag[NT][KC];
#pragma unroll
  for (int nt = 0; nt < NT; ++nt)
#pragma unroll
    for (int kc = 0; kc < KC; ++kc)
      bfrag[nt][kc] = *reinterpret_cast<const bf16x8*>(
          &W2T[(nt * 16 + lr) * KP + kc * 32 + lg * 8]);

  bf16x8 afrag[KC];
#pragma unroll
  for (int kc = 0; kc < KC; ++kc)
    afrag[kc] = *reinterpret_cast<const bf16x8*>(
        &aggT[(wv * 16 + lr) * KP + kc * 32 + lg * 8]);

  f32x4 acc[NT];
#pragma unroll
  for (int nt = 0; nt < NT; ++nt) acc[nt] = (f32x4){0.f, 0.f, 0.f, 0.f};
#pragma unroll
  for (int kc = 0; kc < KC; ++kc)
#pragma unroll
    for (int nt = 0; nt < NT; ++nt)
      acc[nt] = __builtin_amdgcn_mfma_f32_16x16x32_bf16(afrag[kc], bfrag[nt][kc],
                                                        acc[nt], 0, 0, 0);

#pragma unroll
  for (int r = 0; r < 4; ++r) {
    int orow = base + wv * 16 + lg * 4 + r;
    if (orow < n) {
      float sc = dinv[orow];
#pragma unroll
      for (int nt = 0; nt < NT; ++nt)
        h3b[(size_t)orow * 64 + nt * 16 + lr] = (__bf16)(acc[nt][r] * sc);
    }
  }
}

// ---------------- kernel 5: gather2 (branchless 8-wide, sentinel zero row) ----------------

template<int D, bool RELU_OUT, bool OUT_BF16>
__global__ __launch_bounds__(256) void gather_bf_k(const __bf16* __restrict__ h,
                                                   const int* __restrict__ cnt,
                                                   const int* __restrict__ srcs_pad,
                                                   const float* __restrict__ dinv,
                                                   const float* __restrict__ bias,
                                                   void* __restrict__ outv, int n) {
  constexpr int L = D / 8;
  int t = blockIdx.x * 256 + threadIdx.x;
  int node = t / L;
  int d8 = t % L;
  if (node >= n) return;

  int c = cnt[node];
  c = c < PAD ? c : PAD;
  const float di = dinv[node];
  const int* row = srcs_pad + (size_t)node * PAD;
  const bf16x8* h8 = reinterpret_cast<const bf16x8*>(h);
  bf16x8 sv = h8[(size_t)node * L + d8];

  float acc[8];
#pragma unroll
  for (int q = 0; q < 8; ++q) acc[q] = 0.f;

  for (int j0 = 0; j0 < c; j0 += 8) {
    int4 a = *reinterpret_cast<const int4*>(row + j0);
    int4 b = *reinterpret_cast<const int4*>(row + j0 + 4);
    bf16x8 v0 = h8[(size_t)a.x * L + d8];
    bf16x8 v1 = h8[(size_t)a.y * L + d8];
    bf16x8 v2 = h8[(size_t)a.z * L + d8];
    bf16x8 v3 = h8[(size_t)a.w * L + d8];
    bf16x8 v4 = h8[(size_t)b.x * L + d8];
    bf16x8 v5 = h8[(size_t)b.y * L + d8];
    bf16x8 v6 = h8[(size_t)b.z * L + d8];
    bf16x8 v7 = h8[(size_t)b.w * L + d8];
#pragma unroll
    for (int q = 0; q < 8; ++q)
      acc[q] += ((float)v0[q] + (float)v1[q]) + ((float)v2[q] + (float)v3[q]) +
                ((float)v4[q] + (float)v5[q]) + ((float)v6[q] + (float)v7[q]);
  }

  float o[8];
#pragma unroll
  for (int q = 0; q < 8; ++q) {
    float b = bias[d8 * 8 + q];
    float val = (acc[q] + (float)sv[q]) * di + b;
    o[q] = RELU_OUT ? fmaxf(val, 0.f) : val;
  }

  if (OUT_BF16) {
    bf16x8 ov;
#pragma unroll
    for (int q = 0; q < 8; ++q) ov[q] = (__bf16)o[q];
    reinterpret_cast<bf16x8*>(outv)[(size_t)node * L + d8] = ov;
  } else {
    f32x4 lo = {o[0], o[1], o[2], o[3]};
    f32x4 hi = {o[4], o[5], o[6], o[7]};
    f32x4* op = reinterpret_cast<f32x4*>((float*)outv + (size_t)node * D + d8 * 8);
    op[0] = lo;
    op[1] = hi;
  }
}

// ---------------- launch ----------------

extern "C" void kernel_launch(void* const* d_in, const int* in_sizes, int n_in,
                              void* d_out, int out_size, void* d_ws, size_t ws_size,
                              hipStream_t stream) {
  const float* x  = (const float*)d_in[0];
  const int*   ei = (const int*)d_in[1];
  const float* W1 = (const float*)d_in[2];
  const float* b1 = (const float*)d_in[3];
  const float* W2 = (const float*)d_in[4];
  const float* b2 = (const float*)d_in[5];

  const int n = in_sizes[0] / 128;   // 50000
  const int E = in_sizes[1] / 2;     // 800000
  const int* src = ei;
  const int* dst = ei + E;
  float* out = (float*)d_out;

  const int NBIN = (n + ((1 << BIN_SHIFT) - 1)) >> BIN_SHIFT;  // 391

  // workspace (4B words):
  // bincur[NBMAX*CUR_STR] | cnt[n] | dinv[n] | srcs_pad[n*PAD]
  // | h1b[(n+1)*128 bf16] | scratch (bin_data aliases, 391*3072*8 = 9.61MB) | h3b[(n+1)*64 bf16]
  int*   bincur   = (int*)d_ws;
  int*   cnt      = (int*)d_ws + NBMAX * CUR_STR;
  float* dinv     = (float*)d_ws + NBMAX * CUR_STR + n;
  int*   srcs_pad = (int*)d_ws + NBMAX * CUR_STR + 2 * n;
  size_t w = (size_t)NBMAX * CUR_STR + 2 * n + (size_t)n * PAD;
  __bf16* h1b     = (__bf16*)((int*)d_ws + w);   w += (size_t)(n + 1) * 64;
  __bf16* scratch = (__bf16*)((int*)d_ws + w);   w += (size_t)n * 64;
  __bf16* h3b     = (__bf16*)((int*)d_ws + w);
  u64* bin_data = (u64*)scratch;

  init_k<<<1, 256, 0, stream>>>(bincur, h1b + (size_t)n * 128, h3b + (size_t)n * 64);

  // ---- role-split: binning fill (391 blocks) || GEMM1 (128 blocks) ----
  const int fillB = (E + EPB - 1) / EPB;      // 391
  const int gemmB = 128;
  fused_bin_gemm_k<<<fillB + gemmB, 256, 0, stream>>>(
      src, dst, bincur, bin_data, E, fillB, x, W1, h1b, n);

  // ---- padded CSR + cnt/dinv + pre-scale h1b (block == bin) ----
  csr_build_k<<<NBIN, 512, 0, stream>>>(bincur, bin_data, srcs_pad, cnt, dinv, h1b, n);

  // ---- gather1 + GEMM2 fused -> h3b (scaled) ----
  gather_gemm2_k<<<(n + 63) / 64, 256, 0, stream>>>(
      h1b, cnt, srcs_pad, dinv, b1, W2, h3b, n);

  // ---- gather2 -> out (fp32) ----
  {
    long long t = (long long)n * 8;
    gather_bf_k<64, false, false><<<(int)((t + 255) / 256), 256, 0, stream>>>(
        h3b, cnt, srcs_pad, dinv, b2, out, n);
  }
}

// Round 17
// 103.057 us; speedup vs baseline: 1.0289x; 1.0289x over previous
//
#include <hip/hip_runtime.h>

typedef __bf16 bf16x8 __attribute__((ext_vector_type(8)));
typedef __bf16 bf16x4 __attribute__((ext_vector_type(4)));
typedef float  f32x4  __attribute__((ext_vector_type(4)));
typedef unsigned long long u64;

constexpr int PAD       = 64;    // padded CSR row stride
constexpr int BIN_SHIFT = 8;     // 256 nodes / bin -> 196 bins
constexpr int NBMAX     = 256;   // hist/scan array size
constexpr int CAP       = 6144;  // u64 slots per bin (mean 4082, +32 sigma)
constexpr int SUBS      = 2;     // csr_build sub-blocks per bin
constexpr int NPS       = 128;   // nodes per csr_build block
constexpr int STR       = 68;    // csr_build LDS row stride (ints)
constexpr int CUR_STR   = 16;    // bincur: one 64B line per bin
constexpr int EPB       = 2048;  // edges per fill block
constexpr int GGN       = 32;    // nodes per gather_gemm2 block

// ---------------- init: zero bin cursors + sentinel zero-rows ----------------

__global__ void init_k(int* __restrict__ bincur, __bf16* __restrict__ h1zero,
                       __bf16* __restrict__ h3zero) {
  int t = threadIdx.x;
  for (int i = t; i < NBMAX * CUR_STR; i += 256) bincur[i] = 0;
  if (t < 128) h1zero[t] = (__bf16)0.f;
  if (t < 64)  h3zero[t] = (__bf16)0.f;
}

// ---------------- kernel 2: standalone binning fill (r15 structure, 196 bins) ----------------

__global__ __launch_bounds__(256) void bin_fill_k(
    const int* __restrict__ src, const int* __restrict__ dst,
    int* __restrict__ bincur, u64* __restrict__ bin_data, int E, int n) {
  __shared__ u64 pairs[EPB];      // 16384 B
  __shared__ int binof[EPB];      // 8192 B
  __shared__ int hist[NBMAX], cur[NBMAX], sbase[NBMAX], gbase[NBMAX];  // 4096 B

  const int t = threadIdx.x;
  const int NB = (n + ((1 << BIN_SHIFT) - 1)) >> BIN_SHIFT;  // 196

  hist[t] = 0; cur[t] = 0;
  __syncthreads();

  int base_e = blockIdx.x * EPB + t * 8;
  int m = E - base_e;
  m = m < 0 ? 0 : (m > 8 ? 8 : m);

  int sa[8], da[8], ba[8];
  if (m == 8) {
    int4 s0 = *reinterpret_cast<const int4*>(src + base_e);
    int4 s1 = *reinterpret_cast<const int4*>(src + base_e + 4);
    int4 d0 = *reinterpret_cast<const int4*>(dst + base_e);
    int4 d1 = *reinterpret_cast<const int4*>(dst + base_e + 4);
    sa[0]=s0.x; sa[1]=s0.y; sa[2]=s0.z; sa[3]=s0.w;
    sa[4]=s1.x; sa[5]=s1.y; sa[6]=s1.z; sa[7]=s1.w;
    da[0]=d0.x; da[1]=d0.y; da[2]=d0.z; da[3]=d0.w;
    da[4]=d1.x; da[5]=d1.y; da[6]=d1.z; da[7]=d1.w;
  } else {
    for (int k = 0; k < m; ++k) { sa[k] = src[base_e + k]; da[k] = dst[base_e + k]; }
  }
  for (int k = 0; k < m; ++k) {
    ba[k] = da[k] >> BIN_SHIFT;
    atomicAdd(&hist[ba[k]], 1);
  }
  __syncthreads();

  // exclusive scan of hist[0..255] into sbase
  sbase[t] = hist[t];
  __syncthreads();
  for (int off = 1; off < 256; off <<= 1) {
    int u = (t >= off) ? sbase[t - off] : 0;
    __syncthreads();
    sbase[t] += u;
    __syncthreads();
  }
  if (t < NB && hist[t] > 0) gbase[t] = atomicAdd(&bincur[t * CUR_STR], hist[t]);
  sbase[t] -= hist[t];   // inclusive -> exclusive
  __syncthreads();

  for (int k = 0; k < m; ++k) {
    int b = ba[k];
    int q = atomicAdd(&cur[b], 1);
    int slot = sbase[b] + q;
    pairs[slot] = ((u64)(unsigned)sa[k] << 32) | (unsigned)da[k];
    binof[slot] = b;
  }
  __syncthreads();

  int T = E - blockIdx.x * EPB;
  T = T > EPB ? EPB : T;
  for (int i = t; i < T; i += 256) {
    int b = binof[i];
    int pos = gbase[b] + (i - sbase[b]);
    if (pos < CAP) bin_data[(size_t)b * CAP + pos] = pairs[i];
  }
}

// ---------------- kernel 3: standalone GEMM1 (h1b = bf16(x @ W1)) ----------------

__global__ __launch_bounds__(256) void gemm1_k(const float* __restrict__ X,
                                               const float* __restrict__ W,
                                               __bf16* __restrict__ C, int n) {
  constexpr int K = 128, KP = 136, NC = 128, NT = 8, KC = 4;
  __shared__ __bf16 WT[NC * KP];   // 34816 B

  const int t = threadIdx.x;
  for (int idx = t; idx < K * NC / 4; idx += 256) {
    int col = idx & 127;
    int k4  = idx >> 7;
    bf16x4 w;
    w[0] = (__bf16)W[(k4 * 4 + 0) * NC + col];
    w[1] = (__bf16)W[(k4 * 4 + 1) * NC + col];
    w[2] = (__bf16)W[(k4 * 4 + 2) * NC + col];
    w[3] = (__bf16)W[(k4 * 4 + 3) * NC + col];
    *reinterpret_cast<bf16x4*>(&WT[col * KP + k4 * 4]) = w;
  }
  __syncthreads();

  const int lane = t & 63;
  const int lr = lane & 15;
  const int lg = lane >> 4;

  bf16x8 bfrag[NT][KC];
#pragma unroll
  for (int nt = 0; nt < NT; ++nt)
#pragma unroll
    for (int kc = 0; kc < KC; ++kc)
      bfrag[nt][kc] = *reinterpret_cast<const bf16x8*>(
          &WT[(nt * 16 + lr) * KP + kc * 32 + lg * 8]);

  const int gw = blockIdx.x * 4 + (t >> 6);
  const int nw = gridDim.x * 4;
  const int mtiles = (n + 15) / 16;

  for (int mt = gw; mt < mtiles; mt += nw) {
    const int row  = mt * 16 + lr;
    const int crow = (row < n) ? row : (n - 1);

    bf16x8 afrag[KC];
#pragma unroll
    for (int kc = 0; kc < KC; ++kc) {
      const f32x4* p = reinterpret_cast<const f32x4*>(
          X + (size_t)crow * K + kc * 32 + lg * 8);
      f32x4 v0 = p[0], v1 = p[1];
      bf16x8 a;
      a[0] = (__bf16)v0[0]; a[1] = (__bf16)v0[1];
      a[2] = (__bf16)v0[2]; a[3] = (__bf16)v0[3];
      a[4] = (__bf16)v1[0]; a[5] = (__bf16)v1[1];
      a[6] = (__bf16)v1[2]; a[7] = (__bf16)v1[3];
      afrag[kc] = a;
    }

    f32x4 acc[NT];
#pragma unroll
    for (int nt = 0; nt < NT; ++nt) acc[nt] = (f32x4){0.f, 0.f, 0.f, 0.f};
#pragma unroll
    for (int kc = 0; kc < KC; ++kc)
#pragma unroll
      for (int nt = 0; nt < NT; ++nt)
        acc[nt] = __builtin_amdgcn_mfma_f32_16x16x32_bf16(afrag[kc], bfrag[nt][kc],
                                                          acc[nt], 0, 0, 0);

#pragma unroll
    for (int nt = 0; nt < NT; ++nt)
#pragma unroll
      for (int r = 0; r < 4; ++r) {
        int orow = mt * 16 + lg * 4 + r;
        if (orow < n) C[(size_t)orow * NC + nt * 16 + lr] = (__bf16)acc[nt][r];
      }
  }
}

// ---------------- kernel 4: bins -> padded CSR + cnt/dinv + h1b*=dinv (SUBS=2) ----------------

__global__ __launch_bounds__(512) void csr_build_k(const int* __restrict__ bincur,
                                                   const u64* __restrict__ bin_data,
                                                   int* __restrict__ srcs_pad,
                                                   int* __restrict__ cnt,
                                                   float* __restrict__ dinv,
                                                   __bf16* __restrict__ h1b, int n) {
  __shared__ int rows[NPS * STR];   // 34816 B
  __shared__ int lcnt[NPS];

  const int bin = blockIdx.x / SUBS;
  const int sub = blockIdx.x % SUBS;
  const int lo  = (bin << BIN_SHIFT) + sub * NPS;
  const int hi  = min(n, lo + NPS);

  for (int i = threadIdx.x; i < NPS * STR; i += 512) rows[i] = n;  // sentinel
  for (int i = threadIdx.x; i < NPS; i += 512) lcnt[i] = 0;
  __syncthreads();

  int cntE = bincur[bin * CUR_STR];
  cntE = cntE < CAP ? cntE : CAP;
  const u64* bd = bin_data + (size_t)bin * CAP;

  for (int i = threadIdx.x; i < cntE; i += 512) {
    u64 p = bd[i];
    int d = (int)(p & 0xffffffffu);
    unsigned l = (unsigned)(d - lo);
    if (l < (unsigned)NPS) {
      int q = atomicAdd(&lcnt[l], 1);
      if (q < PAD) rows[l * STR + q] = (int)(p >> 32);
    }
  }
  __syncthreads();

  for (int i = threadIdx.x; i < NPS * (PAD / 4); i += 512) {
    int nl = i >> 4;
    int c4 = i & 15;
    int g = lo + nl;
    if (g < hi)
      *reinterpret_cast<int4*>(&srcs_pad[(size_t)g * PAD + c4 * 4]) =
          *reinterpret_cast<const int4*>(&rows[nl * STR + c4 * 4]);
  }
  for (int i = threadIdx.x; i < NPS; i += 512) {
    int g = lo + i;
    if (g < hi) {
      int c = lcnt[i];
      cnt[g] = c;
      dinv[g] = rsqrtf((float)(c + 1));
    }
  }
  bf16x8* h8 = reinterpret_cast<bf16x8*>(h1b);
  for (int i = threadIdx.x; i < NPS * 16; i += 512) {
    int nl = i >> 4;
    int c8 = i & 15;
    int g = lo + nl;
    if (g < hi) {
      float di = rsqrtf((float)(lcnt[nl] + 1));
      bf16x8 v = h8[(size_t)g * 16 + c8];
      bf16x8 o;
#pragma unroll
      for (int q = 0; q < 8; ++q) o[q] = (__bf16)((float)v[q] * di);
      h8[(size_t)g * 16 + c8] = o;
    }
  }
}

// ---------------- kernel 5: fused {gather1 -> LDS -> GEMM2 -> scaled h3b}, 32 nodes ----------------
// LDS = W2T 17.4KB + aggT 8.7KB = 26.1KB -> 6 blocks/CU; 1563 blocks ~ 6/CU:
// double the waves in flight for the latency-bound gather phase.

__global__ __launch_bounds__(256) void gather_gemm2_k(
    const __bf16* __restrict__ h1b, const int* __restrict__ cnt,
    const int* __restrict__ srcs_pad, const float* __restrict__ dinv,
    const float* __restrict__ b1, const float* __restrict__ W2,
    __bf16* __restrict__ h3b, int n) {
  constexpr int K  = 128;
  constexpr int KP = 136;
  constexpr int KC = 4;

  __shared__ __bf16 W2T[64 * KP];    // 17408 B
  __shared__ __bf16 aggT[GGN * KP];  // 8704 B

  const int t = threadIdx.x;

  // coalesced col-major W2 staging
  for (int idx = t; idx < K * 64 / 4; idx += 256) {
    int col = idx & 63;
    int k4  = idx >> 6;
    bf16x4 w;
    w[0] = (__bf16)W2[(k4 * 4 + 0) * 64 + col];
    w[1] = (__bf16)W2[(k4 * 4 + 1) * 64 + col];
    w[2] = (__bf16)W2[(k4 * 4 + 2) * 64 + col];
    w[3] = (__bf16)W2[(k4 * 4 + 3) * 64 + col];
    *reinterpret_cast<bf16x4*>(&W2T[col * KP + k4 * 4]) = w;
  }

  // phase A: gather 32 nodes' agg rows into aggT (2 passes of 16 nodes)
  const int base = blockIdx.x * GGN;
  const bf16x8* h8 = reinterpret_cast<const bf16x8*>(h1b);
#pragma unroll
  for (int pass = 0; pass < 2; ++pass) {
    const int nl = pass * 16 + (t >> 4);   // 0..31
    const int d8 = t & 15;
    const int node = base + nl;
    bf16x8 ov;
    if (node < n) {
      int c = cnt[node];
      c = c < PAD ? c : PAD;
      const float di = dinv[node];
      const int* row = srcs_pad + (size_t)node * PAD;
      bf16x8 sv = h8[(size_t)node * 16 + d8];

      float acc[8];
#pragma unroll
      for (int q = 0; q < 8; ++q) acc[q] = 0.f;

      for (int j0 = 0; j0 < c; j0 += 8) {
        int4 a = *reinterpret_cast<const int4*>(row + j0);
        int4 b = *reinterpret_cast<const int4*>(row + j0 + 4);
        bf16x8 v0 = h8[(size_t)a.x * 16 + d8];
        bf16x8 v1 = h8[(size_t)a.y * 16 + d8];
        bf16x8 v2 = h8[(size_t)a.z * 16 + d8];
        bf16x8 v3 = h8[(size_t)a.w * 16 + d8];
        bf16x8 v4 = h8[(size_t)b.x * 16 + d8];
        bf16x8 v5 = h8[(size_t)b.y * 16 + d8];
        bf16x8 v6 = h8[(size_t)b.z * 16 + d8];
        bf16x8 v7 = h8[(size_t)b.w * 16 + d8];
#pragma unroll
        for (int q = 0; q < 8; ++q)
          acc[q] += ((float)v0[q] + (float)v1[q]) + ((float)v2[q] + (float)v3[q]) +
                    ((float)v4[q] + (float)v5[q]) + ((float)v6[q] + (float)v7[q]);
      }
#pragma unroll
      for (int q = 0; q < 8; ++q) {
        float val = (acc[q] + (float)sv[q]) * di + b1[d8 * 8 + q];
        ov[q] = (__bf16)fmaxf(val, 0.f);
      }
    } else {
#pragma unroll
      for (int q = 0; q < 8; ++q) ov[q] = (__bf16)0.f;
    }
    *reinterpret_cast<bf16x8*>(&aggT[nl * KP + d8 * 8]) = ov;
  }
  __syncthreads();

  // phase B: 4 waves, each: 1 M-tile (16 rows) x 2 column-tiles
  const int lane = t & 63;
  const int lr = lane & 15;
  const int lg = lane >> 4;
  const int wv = t >> 6;
  const int mrow = (wv & 1) * 16;   // 0 or 16
  const int ch   = wv >> 1;         // column half: cols [ch*32, ch*32+32)

  bf16x8 bfrag[2][KC];
#pragma unroll
  for (int nt = 0; nt < 2; ++nt)
#pragma unroll
    for (int kc = 0; kc < KC; ++kc)
      bfrag[nt][kc] = *reinterpret_cast<const bf16x8*>(
          &W2T[((ch * 2 + nt) * 16 + lr) * KP + kc * 32 + lg * 8]);

  bf16x8 afrag[KC];
#pragma unroll
  for (int kc = 0; kc < KC; ++kc)
    afrag[kc] = *reinterpret_cast<const bf16x8*>(
        &aggT[(mrow + lr) * KP + kc * 32 + lg * 8]);

  f32x4 acc[2];
#pragma unroll
  for (int nt = 0; nt < 2; ++nt) acc[nt] = (f32x4){0.f, 0.f, 0.f, 0.f};
#pragma unroll
  for (int kc = 0; kc < KC; ++kc)
#pragma unroll
    for (int nt = 0; nt < 2; ++nt)
      acc[nt] = __builtin_amdgcn_mfma_f32_16x16x32_bf16(afrag[kc], bfrag[nt][kc],
                                                        acc[nt], 0, 0, 0);

#pragma unroll
  for (int r = 0; r < 4; ++r) {
    int orow = base + mrow + lg * 4 + r;
    if (orow < n) {
      float sc = dinv[orow];
#pragma unroll
      for (int nt = 0; nt < 2; ++nt)
        h3b[(size_t)orow * 64 + (ch * 2 + nt) * 16 + lr] = (__bf16)(acc[nt][r] * sc);
    }
  }
}

// ---------------- kernel 6: gather2 (branchless 8-wide, sentinel zero row) ----------------

template<int D, bool RELU_OUT, bool OUT_BF16>
__global__ __launch_bounds__(256) void gather_bf_k(const __bf16* __restrict__ h,
                                                   const int* __restrict__ cnt,
                                                   const int* __restrict__ srcs_pad,
                                                   const float* __restrict__ dinv,
                                                   const float* __restrict__ bias,
                                                   void* __restrict__ outv, int n) {
  constexpr int L = D / 8;
  int t = blockIdx.x * 256 + threadIdx.x;
  int node = t / L;
  int d8 = t % L;
  if (node >= n) return;

  int c = cnt[node];
  c = c < PAD ? c : PAD;
  const float di = dinv[node];
  const int* row = srcs_pad + (size_t)node * PAD;
  const bf16x8* h8 = reinterpret_cast<const bf16x8*>(h);
  bf16x8 sv = h8[(size_t)node * L + d8];

  float acc[8];
#pragma unroll
  for (int q = 0; q < 8; ++q) acc[q] = 0.f;

  for (int j0 = 0; j0 < c; j0 += 8) {
    int4 a = *reinterpret_cast<const int4*>(row + j0);
    int4 b = *reinterpret_cast<const int4*>(row + j0 + 4);
    bf16x8 v0 = h8[(size_t)a.x * L + d8];
    bf16x8 v1 = h8[(size_t)a.y * L + d8];
    bf16x8 v2 = h8[(size_t)a.z * L + d8];
    bf16x8 v3 = h8[(size_t)a.w * L + d8];
    bf16x8 v4 = h8[(size_t)b.x * L + d8];
    bf16x8 v5 = h8[(size_t)b.y * L + d8];
    bf16x8 v6 = h8[(size_t)b.z * L + d8];
    bf16x8 v7 = h8[(size_t)b.w * L + d8];
#pragma unroll
    for (int q = 0; q < 8; ++q)
      acc[q] += ((float)v0[q] + (float)v1[q]) + ((float)v2[q] + (float)v3[q]) +
                ((float)v4[q] + (float)v5[q]) + ((float)v6[q] + (float)v7[q]);
  }

  float o[8];
#pragma unroll
  for (int q = 0; q < 8; ++q) {
    float b = bias[d8 * 8 + q];
    float val = (acc[q] + (float)sv[q]) * di + b;
    o[q] = RELU_OUT ? fmaxf(val, 0.f) : val;
  }

  if (OUT_BF16) {
    bf16x8 ov;
#pragma unroll
    for (int q = 0; q < 8; ++q) ov[q] = (__bf16)o[q];
    reinterpret_cast<bf16x8*>(outv)[(size_t)node * L + d8] = ov;
  } else {
    f32x4 lo = {o[0], o[1], o[2], o[3]};
    f32x4 hi = {o[4], o[5], o[6], o[7]};
    f32x4* op = reinterpret_cast<f32x4*>((float*)outv + (size_t)node * D + d8 * 8);
    op[0] = lo;
    op[1] = hi;
  }
}

// ---------------- launch ----------------

extern "C" void kernel_launch(void* const* d_in, const int* in_sizes, int n_in,
                              void* d_out, int out_size, void* d_ws, size_t ws_size,
                              hipStream_t stream) {
  const float* x  = (const float*)d_in[0];
  const int*   ei = (const int*)d_in[1];
  const float* W1 = (const float*)d_in[2];
  const float* b1 = (const float*)d_in[3];
  const float* W2 = (const float*)d_in[4];
  const float* b2 = (const float*)d_in[5];

  const int n = in_sizes[0] / 128;   // 50000
  const int E = in_sizes[1] / 2;     // 800000
  const int* src = ei;
  const int* dst = ei + E;
  float* out = (float*)d_out;

  const int NBIN = (n + ((1 << BIN_SHIFT) - 1)) >> BIN_SHIFT;  // 196

  // workspace (4B words):
  // bincur[NBMAX*CUR_STR] | cnt[n] | dinv[n] | srcs_pad[n*PAD]
  // | h1b[(n+1)*128 bf16] | scratch (bin_data aliases, 196*6144*8 = 9.6MB) | h3b[(n+1)*64 bf16]
  int*   bincur   = (int*)d_ws;
  int*   cnt      = (int*)d_ws + NBMAX * CUR_STR;
  float* dinv     = (float*)d_ws + NBMAX * CUR_STR + n;
  int*   srcs_pad = (int*)d_ws + NBMAX * CUR_STR + 2 * n;
  size_t w = (size_t)NBMAX * CUR_STR + 2 * n + (size_t)n * PAD;
  __bf16* h1b     = (__bf16*)((int*)d_ws + w);   w += (size_t)(n + 1) * 64;
  __bf16* scratch = (__bf16*)((int*)d_ws + w);   w += (size_t)n * 64;
  __bf16* h3b     = (__bf16*)((int*)d_ws + w);
  u64* bin_data = (u64*)scratch;

  init_k<<<1, 256, 0, stream>>>(bincur, h1b + (size_t)n * 128, h3b + (size_t)n * 64);

  // ---- binning fill (standalone, r15-proven structure) ----
  const int fillB = (E + EPB - 1) / EPB;      // 391
  bin_fill_k<<<fillB, 256, 0, stream>>>(src, dst, bincur, bin_data, E, n);

  // ---- GEMM1 (standalone) ----
  gemm1_k<<<256, 256, 0, stream>>>(x, W1, h1b, n);

  // ---- padded CSR + cnt/dinv + pre-scale h1b (SUBS=2) ----
  csr_build_k<<<NBIN * SUBS, 512, 0, stream>>>(bincur, bin_data, srcs_pad, cnt, dinv, h1b, n);

  // ---- gather1 + GEMM2 fused -> h3b (scaled), 32 nodes/block ----
  gather_gemm2_k<<<(n + GGN - 1) / GGN, 256, 0, stream>>>(
      h1b, cnt, srcs_pad, dinv, b1, W2, h3b, n);

  // ---- gather2 -> out (fp32) ----
  {
    long long t = (long long)n * 8;
    gather_bf_k<64, false, false><<<(int)((t + 255) / 256), 256, 0, stream>>>(
        h3b, cnt, srcs_pad, dinv, b2, out, n);
  }
}

// Round 18
// 102.968 us; speedup vs baseline: 1.0298x; 1.0009x over previous
//
#include <hip/hip_runtime.h>

typedef __bf16 bf16x8 __attribute__((ext_vector_type(8)));
typedef __bf16 bf16x4 __attribute__((ext_vector_type(4)));
typedef float  f32x4  __attribute__((ext_vector_type(4)));
typedef unsigned long long u64;

constexpr int PAD       = 64;    // padded CSR row stride
constexpr int BIN_SHIFT = 8;     // 256 nodes / bin -> 196 bins
constexpr int NBMAX     = 256;   // hist array size
constexpr int CAP       = 6144;  // u64 slots per bin (mean 4082, +32 sigma)
constexpr int SUBS      = 2;     // csr_build sub-blocks per bin
constexpr int NPS       = 128;   // nodes per csr_build block
constexpr int STR       = 68;    // csr_build LDS row stride (ints)
constexpr int CUR_STR   = 16;    // bincur: one 64B line per bin
constexpr int EPB       = 2048;  // edges per fill block
constexpr int GGN       = 32;    // nodes per gather_gemm2 block

// ---------------- init: zero bin cursors + sentinel zero-rows ----------------

__global__ void init_k(int* __restrict__ bincur, __bf16* __restrict__ h1zero,
                       __bf16* __restrict__ h3zero) {
  int t = threadIdx.x;
  for (int i = t; i < NBMAX * CUR_STR; i += 256) bincur[i] = 0;
  if (t < 128) h1zero[t] = (__bf16)0.f;
  if (t < 64)  h3zero[t] = (__bf16)0.f;
}

// ---------------- kernel 2: binning fill, minimal machinery ----------------
// Rank within (block,bin) comes straight from the LDS hist atomicAdd return;
// edges are stored DIRECTLY at gbase[b]+rank (r12 showed sorted vs scattered
// global stores are indistinguishable here). No scan, no pairs staging, no
// flush pass. LDS 2KB -> 8 blocks/CU.

__global__ __launch_bounds__(256) void bin_fill_k(
    const int* __restrict__ src, const int* __restrict__ dst,
    int* __restrict__ bincur, u64* __restrict__ bin_data, int E, int n) {
  __shared__ int hist[NBMAX];
  __shared__ int gbase[NBMAX];

  const int t = threadIdx.x;
  hist[t] = 0;
  __syncthreads();

  int base_e = blockIdx.x * EPB + t * 8;
  int m = E - base_e;
  m = m < 0 ? 0 : (m > 8 ? 8 : m);

  int sa[8], da[8], ba[8], ra[8];
  if (m == 8) {
    int4 s0 = *reinterpret_cast<const int4*>(src + base_e);
    int4 s1 = *reinterpret_cast<const int4*>(src + base_e + 4);
    int4 d0 = *reinterpret_cast<const int4*>(dst + base_e);
    int4 d1 = *reinterpret_cast<const int4*>(dst + base_e + 4);
    sa[0]=s0.x; sa[1]=s0.y; sa[2]=s0.z; sa[3]=s0.w;
    sa[4]=s1.x; sa[5]=s1.y; sa[6]=s1.z; sa[7]=s1.w;
    da[0]=d0.x; da[1]=d0.y; da[2]=d0.z; da[3]=d0.w;
    da[4]=d1.x; da[5]=d1.y; da[6]=d1.z; da[7]=d1.w;
  } else {
    for (int k = 0; k < m; ++k) { sa[k] = src[base_e + k]; da[k] = dst[base_e + k]; }
  }
  for (int k = 0; k < m; ++k) {
    ba[k] = da[k] >> BIN_SHIFT;
    ra[k] = atomicAdd(&hist[ba[k]], 1);   // rank within (block, bin)
  }
  __syncthreads();

  if (hist[t] > 0) gbase[t] = atomicAdd(&bincur[t * CUR_STR], hist[t]);
  __syncthreads();

  for (int k = 0; k < m; ++k) {
    int pos = gbase[ba[k]] + ra[k];
    if (pos < CAP)
      bin_data[(size_t)ba[k] * CAP + pos] = ((u64)(unsigned)sa[k] << 32) | (unsigned)da[k];
  }
}

// ---------------- kernel 3: standalone GEMM1 (h1b = bf16(x @ W1)) ----------------

__global__ __launch_bounds__(256) void gemm1_k(const float* __restrict__ X,
                                               const float* __restrict__ W,
                                               __bf16* __restrict__ C, int n) {
  constexpr int K = 128, KP = 136, NC = 128, NT = 8, KC = 4;
  __shared__ __bf16 WT[NC * KP];   // 34816 B

  const int t = threadIdx.x;
  for (int idx = t; idx < K * NC / 4; idx += 256) {
    int col = idx & 127;
    int k4  = idx >> 7;
    bf16x4 w;
    w[0] = (__bf16)W[(k4 * 4 + 0) * NC + col];
    w[1] = (__bf16)W[(k4 * 4 + 1) * NC + col];
    w[2] = (__bf16)W[(k4 * 4 + 2) * NC + col];
    w[3] = (__bf16)W[(k4 * 4 + 3) * NC + col];
    *reinterpret_cast<bf16x4*>(&WT[col * KP + k4 * 4]) = w;
  }
  __syncthreads();

  const int lane = t & 63;
  const int lr = lane & 15;
  const int lg = lane >> 4;

  bf16x8 bfrag[NT][KC];
#pragma unroll
  for (int nt = 0; nt < NT; ++nt)
#pragma unroll
    for (int kc = 0; kc < KC; ++kc)
      bfrag[nt][kc] = *reinterpret_cast<const bf16x8*>(
          &WT[(nt * 16 + lr) * KP + kc * 32 + lg * 8]);

  const int gw = blockIdx.x * 4 + (t >> 6);
  const int nw = gridDim.x * 4;
  const int mtiles = (n + 15) / 16;

  for (int mt = gw; mt < mtiles; mt += nw) {
    const int row  = mt * 16 + lr;
    const int crow = (row < n) ? row : (n - 1);

    bf16x8 afrag[KC];
#pragma unroll
    for (int kc = 0; kc < KC; ++kc) {
      const f32x4* p = reinterpret_cast<const f32x4*>(
          X + (size_t)crow * K + kc * 32 + lg * 8);
      f32x4 v0 = p[0], v1 = p[1];
      bf16x8 a;
      a[0] = (__bf16)v0[0]; a[1] = (__bf16)v0[1];
      a[2] = (__bf16)v0[2]; a[3] = (__bf16)v0[3];
      a[4] = (__bf16)v1[0]; a[5] = (__bf16)v1[1];
      a[6] = (__bf16)v1[2]; a[7] = (__bf16)v1[3];
      afrag[kc] = a;
    }

    f32x4 acc[NT];
#pragma unroll
    for (int nt = 0; nt < NT; ++nt) acc[nt] = (f32x4){0.f, 0.f, 0.f, 0.f};
#pragma unroll
    for (int kc = 0; kc < KC; ++kc)
#pragma unroll
      for (int nt = 0; nt < NT; ++nt)
        acc[nt] = __builtin_amdgcn_mfma_f32_16x16x32_bf16(afrag[kc], bfrag[nt][kc],
                                                          acc[nt], 0, 0, 0);

#pragma unroll
    for (int nt = 0; nt < NT; ++nt)
#pragma unroll
      for (int r = 0; r < 4; ++r) {
        int orow = mt * 16 + lg * 4 + r;
        if (orow < n) C[(size_t)orow * NC + nt * 16 + lr] = (__bf16)acc[nt][r];
      }
  }
}

// ---------------- kernel 4: bins -> padded CSR + cnt/dinv + h1b*=dinv (SUBS=2) ----------------

__global__ __launch_bounds__(512) void csr_build_k(const int* __restrict__ bincur,
                                                   const u64* __restrict__ bin_data,
                                                   int* __restrict__ srcs_pad,
                                                   int* __restrict__ cnt,
                                                   float* __restrict__ dinv,
                                                   __bf16* __restrict__ h1b, int n) {
  __shared__ int rows[NPS * STR];   // 34816 B
  __shared__ int lcnt[NPS];

  const int bin = blockIdx.x / SUBS;
  const int sub = blockIdx.x % SUBS;
  const int lo  = (bin << BIN_SHIFT) + sub * NPS;
  const int hi  = min(n, lo + NPS);

  for (int i = threadIdx.x; i < NPS * STR; i += 512) rows[i] = n;  // sentinel
  for (int i = threadIdx.x; i < NPS; i += 512) lcnt[i] = 0;
  __syncthreads();

  int cntE = bincur[bin * CUR_STR];
  cntE = cntE < CAP ? cntE : CAP;
  const u64* bd = bin_data + (size_t)bin * CAP;

  for (int i = threadIdx.x; i < cntE; i += 512) {
    u64 p = bd[i];
    int d = (int)(p & 0xffffffffu);
    unsigned l = (unsigned)(d - lo);
    if (l < (unsigned)NPS) {
      int q = atomicAdd(&lcnt[l], 1);
      if (q < PAD) rows[l * STR + q] = (int)(p >> 32);
    }
  }
  __syncthreads();

  for (int i = threadIdx.x; i < NPS * (PAD / 4); i += 512) {
    int nl = i >> 4;
    int c4 = i & 15;
    int g = lo + nl;
    if (g < hi)
      *reinterpret_cast<int4*>(&srcs_pad[(size_t)g * PAD + c4 * 4]) =
          *reinterpret_cast<const int4*>(&rows[nl * STR + c4 * 4]);
  }
  for (int i = threadIdx.x; i < NPS; i += 512) {
    int g = lo + i;
    if (g < hi) {
      int c = lcnt[i];
      cnt[g] = c;
      dinv[g] = rsqrtf((float)(c + 1));
    }
  }
  bf16x8* h8 = reinterpret_cast<bf16x8*>(h1b);
  for (int i = threadIdx.x; i < NPS * 16; i += 512) {
    int nl = i >> 4;
    int c8 = i & 15;
    int g = lo + nl;
    if (g < hi) {
      float di = rsqrtf((float)(lcnt[nl] + 1));
      bf16x8 v = h8[(size_t)g * 16 + c8];
      bf16x8 o;
#pragma unroll
      for (int q = 0; q < 8; ++q) o[q] = (__bf16)((float)v[q] * di);
      h8[(size_t)g * 16 + c8] = o;
    }
  }
}

// ---------------- kernel 5: fused {gather1 -> LDS -> GEMM2 -> scaled h3b}, 32 nodes ----------------

__global__ __launch_bounds__(256) void gather_gemm2_k(
    const __bf16* __restrict__ h1b, const int* __restrict__ cnt,
    const int* __restrict__ srcs_pad, const float* __restrict__ dinv,
    const float* __restrict__ b1, const float* __restrict__ W2,
    __bf16* __restrict__ h3b, int n) {
  constexpr int K  = 128;
  constexpr int KP = 136;
  constexpr int KC = 4;

  __shared__ __bf16 W2T[64 * KP];    // 17408 B
  __shared__ __bf16 aggT[GGN * KP];  // 8704 B

  const int t = threadIdx.x;

  for (int idx = t; idx < K * 64 / 4; idx += 256) {
    int col = idx & 63;
    int k4  = idx >> 6;
    bf16x4 w;
    w[0] = (__bf16)W2[(k4 * 4 + 0) * 64 + col];
    w[1] = (__bf16)W2[(k4 * 4 + 1) * 64 + col];
    w[2] = (__bf16)W2[(k4 * 4 + 2) * 64 + col];
    w[3] = (__bf16)W2[(k4 * 4 + 3) * 64 + col];
    *reinterpret_cast<bf16x4*>(&W2T[col * KP + k4 * 4]) = w;
  }

  const int base = blockIdx.x * GGN;
  const bf16x8* h8 = reinterpret_cast<const bf16x8*>(h1b);
#pragma unroll
  for (int pass = 0; pass < 2; ++pass) {
    const int nl = pass * 16 + (t >> 4);
    const int d8 = t & 15;
    const int node = base + nl;
    bf16x8 ov;
    if (node < n) {
      int c = cnt[node];
      c = c < PAD ? c : PAD;
      const float di = dinv[node];
      const int* row = srcs_pad + (size_t)node * PAD;
      bf16x8 sv = h8[(size_t)node * 16 + d8];

      float acc[8];
#pragma unroll
      for (int q = 0; q < 8; ++q) acc[q] = 0.f;

      for (int j0 = 0; j0 < c; j0 += 8) {
        int4 a = *reinterpret_cast<const int4*>(row + j0);
        int4 b = *reinterpret_cast<const int4*>(row + j0 + 4);
        bf16x8 v0 = h8[(size_t)a.x * 16 + d8];
        bf16x8 v1 = h8[(size_t)a.y * 16 + d8];
        bf16x8 v2 = h8[(size_t)a.z * 16 + d8];
        bf16x8 v3 = h8[(size_t)a.w * 16 + d8];
        bf16x8 v4 = h8[(size_t)b.x * 16 + d8];
        bf16x8 v5 = h8[(size_t)b.y * 16 + d8];
        bf16x8 v6 = h8[(size_t)b.z * 16 + d8];
        bf16x8 v7 = h8[(size_t)b.w * 16 + d8];
#pragma unroll
        for (int q = 0; q < 8; ++q)
          acc[q] += ((float)v0[q] + (float)v1[q]) + ((float)v2[q] + (float)v3[q]) +
                    ((float)v4[q] + (float)v5[q]) + ((float)v6[q] + (float)v7[q]);
      }
#pragma unroll
      for (int q = 0; q < 8; ++q) {
        float val = (acc[q] + (float)sv[q]) * di + b1[d8 * 8 + q];
        ov[q] = (__bf16)fmaxf(val, 0.f);
      }
    } else {
#pragma unroll
      for (int q = 0; q < 8; ++q) ov[q] = (__bf16)0.f;
    }
    *reinterpret_cast<bf16x8*>(&aggT[nl * KP + d8 * 8]) = ov;
  }
  __syncthreads();

  const int lane = t & 63;
  const int lr = lane & 15;
  const int lg = lane >> 4;
  const int wv = t >> 6;
  const int mrow = (wv & 1) * 16;
  const int ch   = wv >> 1;

  bf16x8 bfrag[2][KC];
#pragma unroll
  for (int nt = 0; nt < 2; ++nt)
#pragma unroll
    for (int kc = 0; kc < KC; ++kc)
      bfrag[nt][kc] = *reinterpret_cast<const bf16x8*>(
          &W2T[((ch * 2 + nt) * 16 + lr) * KP + kc * 32 + lg * 8]);

  bf16x8 afrag[KC];
#pragma unroll
  for (int kc = 0; kc < KC; ++kc)
    afrag[kc] = *reinterpret_cast<const bf16x8*>(
        &aggT[(mrow + lr) * KP + kc * 32 + lg * 8]);

  f32x4 acc[2];
#pragma unroll
  for (int nt = 0; nt < 2; ++nt) acc[nt] = (f32x4){0.f, 0.f, 0.f, 0.f};
#pragma unroll
  for (int kc = 0; kc < KC; ++kc)
#pragma unroll
    for (int nt = 0; nt < 2; ++nt)
      acc[nt] = __builtin_amdgcn_mfma_f32_16x16x32_bf16(afrag[kc], bfrag[nt][kc],
                                                        acc[nt], 0, 0, 0);

#pragma unroll
  for (int r = 0; r < 4; ++r) {
    int orow = base + mrow + lg * 4 + r;
    if (orow < n) {
      float sc = dinv[orow];
#pragma unroll
      for (int nt = 0; nt < 2; ++nt)
        h3b[(size_t)orow * 64 + (ch * 2 + nt) * 16 + lr] = (__bf16)(acc[nt][r] * sc);
    }
  }
}

// ---------------- kernel 6: gather2 (branchless 8-wide, sentinel zero row) ----------------

template<int D, bool RELU_OUT, bool OUT_BF16>
__global__ __launch_bounds__(256) void gather_bf_k(const __bf16* __restrict__ h,
                                                   const int* __restrict__ cnt,
                                                   const int* __restrict__ srcs_pad,
                                                   const float* __restrict__ dinv,
                                                   const float* __restrict__ bias,
                                                   void* __restrict__ outv, int n) {
  constexpr int L = D / 8;
  int t = blockIdx.x * 256 + threadIdx.x;
  int node = t / L;
  int d8 = t % L;
  if (node >= n) return;

  int c = cnt[node];
  c = c < PAD ? c : PAD;
  const float di = dinv[node];
  const int* row = srcs_pad + (size_t)node * PAD;
  const bf16x8* h8 = reinterpret_cast<const bf16x8*>(h);
  bf16x8 sv = h8[(size_t)node * L + d8];

  float acc[8];
#pragma unroll
  for (int q = 0; q < 8; ++q) acc[q] = 0.f;

  for (int j0 = 0; j0 < c; j0 += 8) {
    int4 a = *reinterpret_cast<const int4*>(row + j0);
    int4 b = *reinterpret_cast<const int4*>(row + j0 + 4);
    bf16x8 v0 = h8[(size_t)a.x * L + d8];
    bf16x8 v1 = h8[(size_t)a.y * L + d8];
    bf16x8 v2 = h8[(size_t)a.z * L + d8];
    bf16x8 v3 = h8[(size_t)a.w * L + d8];
    bf16x8 v4 = h8[(size_t)b.x * L + d8];
    bf16x8 v5 = h8[(size_t)b.y * L + d8];
    bf16x8 v6 = h8[(size_t)b.z * L + d8];
    bf16x8 v7 = h8[(size_t)b.w * L + d8];
#pragma unroll
    for (int q = 0; q < 8; ++q)
      acc[q] += ((float)v0[q] + (float)v1[q]) + ((float)v2[q] + (float)v3[q]) +
                ((float)v4[q] + (float)v5[q]) + ((float)v6[q] + (float)v7[q]);
  }

  float o[8];
#pragma unroll
  for (int q = 0; q < 8; ++q) {
    float b = bias[d8 * 8 + q];
    float val = (acc[q] + (float)sv[q]) * di + b;
    o[q] = RELU_OUT ? fmaxf(val, 0.f) : val;
  }

  if (OUT_BF16) {
    bf16x8 ov;
#pragma unroll
    for (int q = 0; q < 8; ++q) ov[q] = (__bf16)o[q];
    reinterpret_cast<bf16x8*>(outv)[(size_t)node * L + d8] = ov;
  } else {
    f32x4 lo = {o[0], o[1], o[2], o[3]};
    f32x4 hi = {o[4], o[5], o[6], o[7]};
    f32x4* op = reinterpret_cast<f32x4*>((float*)outv + (size_t)node * D + d8 * 8);
    op[0] = lo;
    op[1] = hi;
  }
}

// ---------------- launch ----------------

extern "C" void kernel_launch(void* const* d_in, const int* in_sizes, int n_in,
                              void* d_out, int out_size, void* d_ws, size_t ws_size,
                              hipStream_t stream) {
  const float* x  = (const float*)d_in[0];
  const int*   ei = (const int*)d_in[1];
  const float* W1 = (const float*)d_in[2];
  const float* b1 = (const float*)d_in[3];
  const float* W2 = (const float*)d_in[4];
  const float* b2 = (const float*)d_in[5];

  const int n = in_sizes[0] / 128;   // 50000
  const int E = in_sizes[1] / 2;     // 800000
  const int* src = ei;
  const int* dst = ei + E;
  float* out = (float*)d_out;

  const int NBIN = (n + ((1 << BIN_SHIFT) - 1)) >> BIN_SHIFT;  // 196

  // workspace (4B words):
  // bincur[NBMAX*CUR_STR] | cnt[n] | dinv[n] | srcs_pad[n*PAD]
  // | h1b[(n+1)*128 bf16] | scratch (bin_data aliases, 196*6144*8 = 9.6MB) | h3b[(n+1)*64 bf16]
  int*   bincur   = (int*)d_ws;
  int*   cnt      = (int*)d_ws + NBMAX * CUR_STR;
  float* dinv     = (float*)d_ws + NBMAX * CUR_STR + n;
  int*   srcs_pad = (int*)d_ws + NBMAX * CUR_STR + 2 * n;
  size_t w = (size_t)NBMAX * CUR_STR + 2 * n + (size_t)n * PAD;
  __bf16* h1b     = (__bf16*)((int*)d_ws + w);   w += (size_t)(n + 1) * 64;
  __bf16* scratch = (__bf16*)((int*)d_ws + w);   w += (size_t)n * 64;
  __bf16* h3b     = (__bf16*)((int*)d_ws + w);
  u64* bin_data = (u64*)scratch;

  init_k<<<1, 256, 0, stream>>>(bincur, h1b + (size_t)n * 128, h3b + (size_t)n * 64);

  // ---- binning fill (minimal-machinery) ----
  const int fillB = (E + EPB - 1) / EPB;      // 391
  bin_fill_k<<<fillB, 256, 0, stream>>>(src, dst, bincur, bin_data, E, n);

  // ---- GEMM1 (standalone) ----
  gemm1_k<<<256, 256, 0, stream>>>(x, W1, h1b, n);

  // ---- padded CSR + cnt/dinv + pre-scale h1b (SUBS=2) ----
  csr_build_k<<<NBIN * SUBS, 512, 0, stream>>>(bincur, bin_data, srcs_pad, cnt, dinv, h1b, n);

  // ---- gather1 + GEMM2 fused -> h3b (scaled), 32 nodes/block ----
  gather_gemm2_k<<<(n + GGN - 1) / GGN, 256, 0, stream>>>(
      h1b, cnt, srcs_pad, dinv, b1, W2, h3b, n);

  // ---- gather2 -> out (fp32) ----
  {
    long long t = (long long)n * 8;
    gather_bf_k<64, false, false><<<(int)((t + 255) / 256), 256, 0, stream>>>(
        h3b, cnt, srcs_pad, dinv, b2, out, n);
  }
}

// Round 19
// 98.259 us; speedup vs baseline: 1.0791x; 1.0479x over previous
//
#include <hip/hip_runtime.h>

typedef __bf16 bf16x8 __attribute__((ext_vector_type(8)));
typedef __bf16 bf16x4 __attribute__((ext_vector_type(4)));
typedef float  f32x4  __attribute__((ext_vector_type(4)));
typedef unsigned long long u64;

constexpr int PAD       = 64;    // padded CSR row stride
constexpr int BIN_SHIFT = 8;     // 256 nodes / bin -> 196 bins
constexpr int NBMAX     = 256;   // hist array size
constexpr int CAP       = 6144;  // u64 slots per bin (mean 4082, +32 sigma)
constexpr int SUBS      = 2;     // csr_build sub-blocks per bin
constexpr int NPS       = 128;   // nodes per csr_build block
constexpr int STR       = 68;    // csr_build LDS row stride (ints)
constexpr int CUR_STR   = 16;    // bincur: one 64B line per bin
constexpr int EPB       = 2048;  // edges per fill block
constexpr int GGN       = 32;    // nodes per gather_gemm2 block

// ---------------- init: zero bin cursors + sentinel zero-rows ----------------

__global__ void init_k(int* __restrict__ bincur, __bf16* __restrict__ h1zero,
                       __bf16* __restrict__ h3zero) {
  int t = threadIdx.x;
  for (int i = t; i < NBMAX * CUR_STR; i += 256) bincur[i] = 0;
  if (t < 128) h1zero[t] = (__bf16)0.f;
  if (t < 64)  h3zero[t] = (__bf16)0.f;
}

// ---------------- kernel 2: role-split {minimal fill || 64-col GEMM1} ----------------
// Fill role (blocks [0,fillB)): r18 minimal binning — 2KB of the shared buf.
// GEMM role: stages a 64-column half of W1 (17.4KB) and grid-strides M-tiles.
// Union LDS = 17.4KB -> 8 blocks/CU (thread-limited), so the fill keeps its
// standalone occupancy AND the GEMM hides under its latency stalls.

__global__ __launch_bounds__(256) void fused_fill_gemm_k(
    const int* __restrict__ src, const int* __restrict__ dst,
    int* __restrict__ bincur, u64* __restrict__ bin_data, int E, int fillB,
    const float* __restrict__ X, const float* __restrict__ W,
    __bf16* __restrict__ C, int n) {
  constexpr int K = 128, KP = 136, NC = 128, NT = 4, KC = 4;

  __shared__ __align__(16) char smem[64 * KP * 2];  // 17408 B

  const int t = threadIdx.x;

  if ((int)blockIdx.x < fillB) {
    // ---- fill role: minimal binning (rank from LDS hist atomic) ----
    int* hist  = (int*)smem;            // 1024 B
    int* gbase = (int*)(smem + 1024);   // 1024 B

    hist[t] = 0;
    __syncthreads();

    int base_e = blockIdx.x * EPB + t * 8;
    int m = E - base_e;
    m = m < 0 ? 0 : (m > 8 ? 8 : m);

    int sa[8], da[8], ba[8], ra[8];
    if (m == 8) {
      int4 s0 = *reinterpret_cast<const int4*>(src + base_e);
      int4 s1 = *reinterpret_cast<const int4*>(src + base_e + 4);
      int4 d0 = *reinterpret_cast<const int4*>(dst + base_e);
      int4 d1 = *reinterpret_cast<const int4*>(dst + base_e + 4);
      sa[0]=s0.x; sa[1]=s0.y; sa[2]=s0.z; sa[3]=s0.w;
      sa[4]=s1.x; sa[5]=s1.y; sa[6]=s1.z; sa[7]=s1.w;
      da[0]=d0.x; da[1]=d0.y; da[2]=d0.z; da[3]=d0.w;
      da[4]=d1.x; da[5]=d1.y; da[6]=d1.z; da[7]=d1.w;
    } else {
      for (int k = 0; k < m; ++k) { sa[k] = src[base_e + k]; da[k] = dst[base_e + k]; }
    }
    for (int k = 0; k < m; ++k) {
      ba[k] = da[k] >> BIN_SHIFT;
      ra[k] = atomicAdd(&hist[ba[k]], 1);
    }
    __syncthreads();

    if (hist[t] > 0) gbase[t] = atomicAdd(&bincur[t * CUR_STR], hist[t]);
    __syncthreads();

    for (int k = 0; k < m; ++k) {
      int pos = gbase[ba[k]] + ra[k];
      if (pos < CAP)
        bin_data[(size_t)ba[k] * CAP + pos] = ((u64)(unsigned)sa[k] << 32) | (unsigned)da[k];
    }
    return;
  }

  // ---- GEMM role: C[:, ch*64 .. ch*64+64) = bf16(X @ W1[:, half]) ----
  const int gb = blockIdx.x - fillB;
  const int ch = gb & 1;                 // column half
  __bf16* WT = (__bf16*)smem;            // [64][KP]

  for (int idx = t; idx < K * 64 / 4; idx += 256) {
    int col = idx & 63;
    int k4  = idx >> 6;
    bf16x4 w;
    w[0] = (__bf16)W[(k4 * 4 + 0) * NC + ch * 64 + col];
    w[1] = (__bf16)W[(k4 * 4 + 1) * NC + ch * 64 + col];
    w[2] = (__bf16)W[(k4 * 4 + 2) * NC + ch * 64 + col];
    w[3] = (__bf16)W[(k4 * 4 + 3) * NC + ch * 64 + col];
    *reinterpret_cast<bf16x4*>(&WT[col * KP + k4 * 4]) = w;
  }
  __syncthreads();

  const int lane = t & 63;
  const int lr = lane & 15;
  const int lg = lane >> 4;

  bf16x8 bfrag[NT][KC];
#pragma unroll
  for (int nt = 0; nt < NT; ++nt)
#pragma unroll
    for (int kc = 0; kc < KC; ++kc)
      bfrag[nt][kc] = *reinterpret_cast<const bf16x8*>(
          &WT[(nt * 16 + lr) * KP + kc * 32 + lg * 8]);

  const int gw = (gb >> 1) * 4 + (t >> 6);
  const int nw = ((gridDim.x - fillB) >> 1) * 4;
  const int mtiles = (n + 15) / 16;

  for (int mt = gw; mt < mtiles; mt += nw) {
    const int row  = mt * 16 + lr;
    const int crow = (row < n) ? row : (n - 1);

    bf16x8 afrag[KC];
#pragma unroll
    for (int kc = 0; kc < KC; ++kc) {
      const f32x4* p = reinterpret_cast<const f32x4*>(
          X + (size_t)crow * K + kc * 32 + lg * 8);
      f32x4 v0 = p[0], v1 = p[1];
      bf16x8 a;
      a[0] = (__bf16)v0[0]; a[1] = (__bf16)v0[1];
      a[2] = (__bf16)v0[2]; a[3] = (__bf16)v0[3];
      a[4] = (__bf16)v1[0]; a[5] = (__bf16)v1[1];
      a[6] = (__bf16)v1[2]; a[7] = (__bf16)v1[3];
      afrag[kc] = a;
    }

    f32x4 acc[NT];
#pragma unroll
    for (int nt = 0; nt < NT; ++nt) acc[nt] = (f32x4){0.f, 0.f, 0.f, 0.f};
#pragma unroll
    for (int kc = 0; kc < KC; ++kc)
#pragma unroll
      for (int nt = 0; nt < NT; ++nt)
        acc[nt] = __builtin_amdgcn_mfma_f32_16x16x32_bf16(afrag[kc], bfrag[nt][kc],
                                                          acc[nt], 0, 0, 0);

#pragma unroll
    for (int nt = 0; nt < NT; ++nt)
#pragma unroll
      for (int r = 0; r < 4; ++r) {
        int orow = mt * 16 + lg * 4 + r;
        if (orow < n)
          C[(size_t)orow * NC + ch * 64 + nt * 16 + lr] = (__bf16)acc[nt][r];
      }
  }
}

// ---------------- kernel 3: bins -> padded CSR + cnt/dinv + h1b*=dinv (SUBS=2) ----------------

__global__ __launch_bounds__(512) void csr_build_k(const int* __restrict__ bincur,
                                                   const u64* __restrict__ bin_data,
                                                   int* __restrict__ srcs_pad,
                                                   int* __restrict__ cnt,
                                                   float* __restrict__ dinv,
                                                   __bf16* __restrict__ h1b, int n) {
  __shared__ int rows[NPS * STR];   // 34816 B
  __shared__ int lcnt[NPS];

  const int bin = blockIdx.x / SUBS;
  const int sub = blockIdx.x % SUBS;
  const int lo  = (bin << BIN_SHIFT) + sub * NPS;
  const int hi  = min(n, lo + NPS);

  for (int i = threadIdx.x; i < NPS * STR; i += 512) rows[i] = n;  // sentinel
  for (int i = threadIdx.x; i < NPS; i += 512) lcnt[i] = 0;
  __syncthreads();

  int cntE = bincur[bin * CUR_STR];
  cntE = cntE < CAP ? cntE : CAP;
  const u64* bd = bin_data + (size_t)bin * CAP;

  for (int i = threadIdx.x; i < cntE; i += 512) {
    u64 p = bd[i];
    int d = (int)(p & 0xffffffffu);
    unsigned l = (unsigned)(d - lo);
    if (l < (unsigned)NPS) {
      int q = atomicAdd(&lcnt[l], 1);
      if (q < PAD) rows[l * STR + q] = (int)(p >> 32);
    }
  }
  __syncthreads();

  for (int i = threadIdx.x; i < NPS * (PAD / 4); i += 512) {
    int nl = i >> 4;
    int c4 = i & 15;
    int g = lo + nl;
    if (g < hi)
      *reinterpret_cast<int4*>(&srcs_pad[(size_t)g * PAD + c4 * 4]) =
          *reinterpret_cast<const int4*>(&rows[nl * STR + c4 * 4]);
  }
  for (int i = threadIdx.x; i < NPS; i += 512) {
    int g = lo + i;
    if (g < hi) {
      int c = lcnt[i];
      cnt[g] = c;
      dinv[g] = rsqrtf((float)(c + 1));
    }
  }
  bf16x8* h8 = reinterpret_cast<bf16x8*>(h1b);
  for (int i = threadIdx.x; i < NPS * 16; i += 512) {
    int nl = i >> 4;
    int c8 = i & 15;
    int g = lo + nl;
    if (g < hi) {
      float di = rsqrtf((float)(lcnt[nl] + 1));
      bf16x8 v = h8[(size_t)g * 16 + c8];
      bf16x8 o;
#pragma unroll
      for (int q = 0; q < 8; ++q) o[q] = (__bf16)((float)v[q] * di);
      h8[(size_t)g * 16 + c8] = o;
    }
  }
}

// ---------------- kernel 4: fused {gather1 -> LDS -> GEMM2 -> scaled h3b}, 32 nodes ----------------

__global__ __launch_bounds__(256) void gather_gemm2_k(
    const __bf16* __restrict__ h1b, const int* __restrict__ cnt,
    const int* __restrict__ srcs_pad, const float* __restrict__ dinv,
    const float* __restrict__ b1, const float* __restrict__ W2,
    __bf16* __restrict__ h3b, int n) {
  constexpr int K  = 128;
  constexpr int KP = 136;
  constexpr int KC = 4;

  __shared__ __bf16 W2T[64 * KP];    // 17408 B
  __shared__ __bf16 aggT[GGN * KP];  // 8704 B

  const int t = threadIdx.x;

  for (int idx = t; idx < K * 64 / 4; idx += 256) {
    int col = idx & 63;
    int k4  = idx >> 6;
    bf16x4 w;
    w[0] = (__bf16)W2[(k4 * 4 + 0) * 64 + col];
    w[1] = (__bf16)W2[(k4 * 4 + 1) * 64 + col];
    w[2] = (__bf16)W2[(k4 * 4 + 2) * 64 + col];
    w[3] = (__bf16)W2[(k4 * 4 + 3) * 64 + col];
    *reinterpret_cast<bf16x4*>(&W2T[col * KP + k4 * 4]) = w;
  }

  const int base = blockIdx.x * GGN;
  const bf16x8* h8 = reinterpret_cast<const bf16x8*>(h1b);
#pragma unroll
  for (int pass = 0; pass < 2; ++pass) {
    const int nl = pass * 16 + (t >> 4);
    const int d8 = t & 15;
    const int node = base + nl;
    bf16x8 ov;
    if (node < n) {
      int c = cnt[node];
      c = c < PAD ? c : PAD;
      const float di = dinv[node];
      const int* row = srcs_pad + (size_t)node * PAD;
      bf16x8 sv = h8[(size_t)node * 16 + d8];

      float acc[8];
#pragma unroll
      for (int q = 0; q < 8; ++q) acc[q] = 0.f;

      for (int j0 = 0; j0 < c; j0 += 8) {
        int4 a = *reinterpret_cast<const int4*>(row + j0);
        int4 b = *reinterpret_cast<const int4*>(row + j0 + 4);
        bf16x8 v0 = h8[(size_t)a.x * 16 + d8];
        bf16x8 v1 = h8[(size_t)a.y * 16 + d8];
        bf16x8 v2 = h8[(size_t)a.z * 16 + d8];
        bf16x8 v3 = h8[(size_t)a.w * 16 + d8];
        bf16x8 v4 = h8[(size_t)b.x * 16 + d8];
        bf16x8 v5 = h8[(size_t)b.y * 16 + d8];
        bf16x8 v6 = h8[(size_t)b.z * 16 + d8];
        bf16x8 v7 = h8[(size_t)b.w * 16 + d8];
#pragma unroll
        for (int q = 0; q < 8; ++q)
          acc[q] += ((float)v0[q] + (float)v1[q]) + ((float)v2[q] + (float)v3[q]) +
                    ((float)v4[q] + (float)v5[q]) + ((float)v6[q] + (float)v7[q]);
      }
#pragma unroll
      for (int q = 0; q < 8; ++q) {
        float val = (acc[q] + (float)sv[q]) * di + b1[d8 * 8 + q];
        ov[q] = (__bf16)fmaxf(val, 0.f);
      }
    } else {
#pragma unroll
      for (int q = 0; q < 8; ++q) ov[q] = (__bf16)0.f;
    }
    *reinterpret_cast<bf16x8*>(&aggT[nl * KP + d8 * 8]) = ov;
  }
  __syncthreads();

  const int lane = t & 63;
  const int lr = lane & 15;
  const int lg = lane >> 4;
  const int wv = t >> 6;
  const int mrow = (wv & 1) * 16;
  const int ch   = wv >> 1;

  bf16x8 bfrag[2][KC];
#pragma unroll
  for (int nt = 0; nt < 2; ++nt)
#pragma unroll
    for (int kc = 0; kc < KC; ++kc)
      bfrag[nt][kc] = *reinterpret_cast<const bf16x8*>(
          &W2T[((ch * 2 + nt) * 16 + lr) * KP + kc * 32 + lg * 8]);

  bf16x8 afrag[KC];
#pragma unroll
  for (int kc = 0; kc < KC; ++kc)
    afrag[kc] = *reinterpret_cast<const bf16x8*>(
        &aggT[(mrow + lr) * KP + kc * 32 + lg * 8]);

  f32x4 acc[2];
#pragma unroll
  for (int nt = 0; nt < 2; ++nt) acc[nt] = (f32x4){0.f, 0.f, 0.f, 0.f};
#pragma unroll
  for (int kc = 0; kc < KC; ++kc)
#pragma unroll
    for (int nt = 0; nt < 2; ++nt)
      acc[nt] = __builtin_amdgcn_mfma_f32_16x16x32_bf16(afrag[kc], bfrag[nt][kc],
                                                        acc[nt], 0, 0, 0);

#pragma unroll
  for (int r = 0; r < 4; ++r) {
    int orow = base + mrow + lg * 4 + r;
    if (orow < n) {
      float sc = dinv[orow];
#pragma unroll
      for (int nt = 0; nt < 2; ++nt)
        h3b[(size_t)orow * 64 + (ch * 2 + nt) * 16 + lr] = (__bf16)(acc[nt][r] * sc);
    }
  }
}

// ---------------- kernel 5: gather2 (branchless 8-wide, sentinel zero row) ----------------

template<int D, bool RELU_OUT, bool OUT_BF16>
__global__ __launch_bounds__(256) void gather_bf_k(const __bf16* __restrict__ h,
                                                   const int* __restrict__ cnt,
                                                   const int* __restrict__ srcs_pad,
                                                   const float* __restrict__ dinv,
                                                   const float* __restrict__ bias,
                                                   void* __restrict__ outv, int n) {
  constexpr int L = D / 8;
  int t = blockIdx.x * 256 + threadIdx.x;
  int node = t / L;
  int d8 = t % L;
  if (node >= n) return;

  int c = cnt[node];
  c = c < PAD ? c : PAD;
  const float di = dinv[node];
  const int* row = srcs_pad + (size_t)node * PAD;
  const bf16x8* h8 = reinterpret_cast<const bf16x8*>(h);
  bf16x8 sv = h8[(size_t)node * L + d8];

  float acc[8];
#pragma unroll
  for (int q = 0; q < 8; ++q) acc[q] = 0.f;

  for (int j0 = 0; j0 < c; j0 += 8) {
    int4 a = *reinterpret_cast<const int4*>(row + j0);
    int4 b = *reinterpret_cast<const int4*>(row + j0 + 4);
    bf16x8 v0 = h8[(size_t)a.x * L + d8];
    bf16x8 v1 = h8[(size_t)a.y * L + d8];
    bf16x8 v2 = h8[(size_t)a.z * L + d8];
    bf16x8 v3 = h8[(size_t)a.w * L + d8];
    bf16x8 v4 = h8[(size_t)b.x * L + d8];
    bf16x8 v5 = h8[(size_t)b.y * L + d8];
    bf16x8 v6 = h8[(size_t)b.z * L + d8];
    bf16x8 v7 = h8[(size_t)b.w * L + d8];
#pragma unroll
    for (int q = 0; q < 8; ++q)
      acc[q] += ((float)v0[q] + (float)v1[q]) + ((float)v2[q] + (float)v3[q]) +
                ((float)v4[q] + (float)v5[q]) + ((float)v6[q] + (float)v7[q]);
  }

  float o[8];
#pragma unroll
  for (int q = 0; q < 8; ++q) {
    float b = bias[d8 * 8 + q];
    float val = (acc[q] + (float)sv[q]) * di + b;
    o[q] = RELU_OUT ? fmaxf(val, 0.f) : val;
  }

  if (OUT_BF16) {
    bf16x8 ov;
#pragma unroll
    for (int q = 0; q < 8; ++q) ov[q] = (__bf16)o[q];
    reinterpret_cast<bf16x8*>(outv)[(size_t)node * L + d8] = ov;
  } else {
    f32x4 lo = {o[0], o[1], o[2], o[3]};
    f32x4 hi = {o[4], o[5], o[6], o[7]};
    f32x4* op = reinterpret_cast<f32x4*>((float*)outv + (size_t)node * D + d8 * 8);
    op[0] = lo;
    op[1] = hi;
  }
}

// ---------------- launch ----------------

extern "C" void kernel_launch(void* const* d_in, const int* in_sizes, int n_in,
                              void* d_out, int out_size, void* d_ws, size_t ws_size,
                              hipStream_t stream) {
  const float* x  = (const float*)d_in[0];
  const int*   ei = (const int*)d_in[1];
  const float* W1 = (const float*)d_in[2];
  const float* b1 = (const float*)d_in[3];
  const float* W2 = (const float*)d_in[4];
  const float* b2 = (const float*)d_in[5];

  const int n = in_sizes[0] / 128;   // 50000
  const int E = in_sizes[1] / 2;     // 800000
  const int* src = ei;
  const int* dst = ei + E;
  float* out = (float*)d_out;

  const int NBIN = (n + ((1 << BIN_SHIFT) - 1)) >> BIN_SHIFT;  // 196

  // workspace (4B words):
  // bincur[NBMAX*CUR_STR] | cnt[n] | dinv[n] | srcs_pad[n*PAD]
  // | h1b[(n+1)*128 bf16] | scratch (bin_data aliases, 196*6144*8 = 9.6MB) | h3b[(n+1)*64 bf16]
  int*   bincur   = (int*)d_ws;
  int*   cnt      = (int*)d_ws + NBMAX * CUR_STR;
  float* dinv     = (float*)d_ws + NBMAX * CUR_STR + n;
  int*   srcs_pad = (int*)d_ws + NBMAX * CUR_STR + 2 * n;
  size_t w = (size_t)NBMAX * CUR_STR + 2 * n + (size_t)n * PAD;
  __bf16* h1b     = (__bf16*)((int*)d_ws + w);   w += (size_t)(n + 1) * 64;
  __bf16* scratch = (__bf16*)((int*)d_ws + w);   w += (size_t)n * 64;
  __bf16* h3b     = (__bf16*)((int*)d_ws + w);
  u64* bin_data = (u64*)scratch;

  init_k<<<1, 256, 0, stream>>>(bincur, h1b + (size_t)n * 128, h3b + (size_t)n * 64);

  // ---- role-split: minimal fill (391 blocks, 2KB LDS) || 64-col GEMM1 (256 blocks) ----
  const int fillB = (E + EPB - 1) / EPB;      // 391
  const int gemmB = 256;                      // 128 blocks per column half
  fused_fill_gemm_k<<<fillB + gemmB, 256, 0, stream>>>(
      src, dst, bincur, bin_data, E, fillB, x, W1, h1b, n);

  // ---- padded CSR + cnt/dinv + pre-scale h1b (SUBS=2) ----
  csr_build_k<<<NBIN * SUBS, 512, 0, stream>>>(bincur, bin_data, srcs_pad, cnt, dinv, h1b, n);

  // ---- gather1 + GEMM2 fused -> h3b (scaled), 32 nodes/block ----
  gather_gemm2_k<<<(n + GGN - 1) / GGN, 256, 0, stream>>>(
      h1b, cnt, srcs_pad, dinv, b1, W2, h3b, n);

  // ---- gather2 -> out (fp32) ----
  {
    long long t = (long long)n * 8;
    gather_bf_k<64, false, false><<<(int)((t + 255) / 256), 256, 0, stream>>>(
        h3b, cnt, srcs_pad, dinv, b2, out, n);
  }
}

// Round 20
// 94.138 us; speedup vs baseline: 1.1264x; 1.0438x over previous
//
#include <hip/hip_runtime.h>

typedef __bf16 bf16x8 __attribute__((ext_vector_type(8)));
typedef __bf16 bf16x4 __attribute__((ext_vector_type(4)));
typedef float  f32x4  __attribute__((ext_vector_type(4)));
typedef unsigned long long u64;

constexpr int PAD       = 64;    // padded CSR row stride
constexpr int BIN_SHIFT = 8;     // 256 nodes / bin -> 196 bins
constexpr int NBMAX     = 256;   // hist array size
constexpr int CAP       = 6144;  // u64 slots per bin (mean 4082, +32 sigma)
constexpr int SUBS      = 2;     // csr_build sub-blocks per bin
constexpr int NPS       = 128;   // nodes per csr_build block
constexpr int STR       = 68;    // csr_build LDS row stride (ints)
constexpr int CUR_STR   = 16;    // bincur: one 64B line per bin
constexpr int EPB       = 4096;  // edges per fill block (16/thread) -> 196 blocks
constexpr int GGN       = 32;    // nodes per gather_gemm2 block

// ---------------- init: zero bin cursors + sentinel zero-rows ----------------

__global__ void init_k(int* __restrict__ bincur, __bf16* __restrict__ h1zero,
                       __bf16* __restrict__ h3zero) {
  int t = threadIdx.x;
  for (int i = t; i < NBMAX * CUR_STR; i += 256) bincur[i] = 0;
  if (t < 128) h1zero[t] = (__bf16)0.f;
  if (t < 64)  h3zero[t] = (__bf16)0.f;
}

// ---------------- kernel 2: role-split {minimal fill || 64-col GEMM1} ----------------
// Fill role: 16 edges/thread, rank from LDS hist atomic, direct u64 store at
// gbase[b]+rank. 196 blocks halve the per-bin cursor chain depth (196 RMWs
// per line) and total cursor atomics vs EPB=2048.
// GEMM role: stages a 64-column half of W1 (17.4KB), grid-strides M-tiles.
// Union LDS = 17.4KB -> 8 blocks/CU for both roles.

__global__ __launch_bounds__(256) void fused_fill_gemm_k(
    const int* __restrict__ src, const int* __restrict__ dst,
    int* __restrict__ bincur, u64* __restrict__ bin_data, int E, int fillB,
    const float* __restrict__ X, const float* __restrict__ W,
    __bf16* __restrict__ C, int n) {
  constexpr int K = 128, KP = 136, NC = 128, NT = 4, KC = 4;

  __shared__ __align__(16) char smem[64 * KP * 2];  // 17408 B

  const int t = threadIdx.x;

  if ((int)blockIdx.x < fillB) {
    // ---- fill role ----
    int* hist  = (int*)smem;            // 1024 B
    int* gbase = (int*)(smem + 1024);   // 1024 B

    hist[t] = 0;
    __syncthreads();

    int base_e = blockIdx.x * EPB + t * 16;
    int m = E - base_e;
    m = m < 0 ? 0 : (m > 16 ? 16 : m);

    int sa[16], da[16], ba[16], ra[16];
    if (m == 16) {
#pragma unroll
      for (int q = 0; q < 4; ++q) {
        int4 s = *reinterpret_cast<const int4*>(src + base_e + q * 4);
        int4 d = *reinterpret_cast<const int4*>(dst + base_e + q * 4);
        sa[q*4+0]=s.x; sa[q*4+1]=s.y; sa[q*4+2]=s.z; sa[q*4+3]=s.w;
        da[q*4+0]=d.x; da[q*4+1]=d.y; da[q*4+2]=d.z; da[q*4+3]=d.w;
      }
    } else {
      for (int k = 0; k < m; ++k) { sa[k] = src[base_e + k]; da[k] = dst[base_e + k]; }
    }
    for (int k = 0; k < m; ++k) {
      ba[k] = da[k] >> BIN_SHIFT;
      ra[k] = atomicAdd(&hist[ba[k]], 1);
    }
    __syncthreads();

    if (hist[t] > 0) gbase[t] = atomicAdd(&bincur[t * CUR_STR], hist[t]);
    __syncthreads();

    for (int k = 0; k < m; ++k) {
      int pos = gbase[ba[k]] + ra[k];
      if (pos < CAP)
        bin_data[(size_t)ba[k] * CAP + pos] = ((u64)(unsigned)sa[k] << 32) | (unsigned)da[k];
    }
    return;
  }

  // ---- GEMM role: C[:, ch*64 .. ch*64+64) = bf16(X @ W1[:, half]) ----
  const int gb = blockIdx.x - fillB;
  const int ch = gb & 1;
  __bf16* WT = (__bf16*)smem;            // [64][KP]

  for (int idx = t; idx < K * 64 / 4; idx += 256) {
    int col = idx & 63;
    int k4  = idx >> 6;
    bf16x4 w;
    w[0] = (__bf16)W[(k4 * 4 + 0) * NC + ch * 64 + col];
    w[1] = (__bf16)W[(k4 * 4 + 1) * NC + ch * 64 + col];
    w[2] = (__bf16)W[(k4 * 4 + 2) * NC + ch * 64 + col];
    w[3] = (__bf16)W[(k4 * 4 + 3) * NC + ch * 64 + col];
    *reinterpret_cast<bf16x4*>(&WT[col * KP + k4 * 4]) = w;
  }
  __syncthreads();

  const int lane = t & 63;
  const int lr = lane & 15;
  const int lg = lane >> 4;

  bf16x8 bfrag[NT][KC];
#pragma unroll
  for (int nt = 0; nt < NT; ++nt)
#pragma unroll
    for (int kc = 0; kc < KC; ++kc)
      bfrag[nt][kc] = *reinterpret_cast<const bf16x8*>(
          &WT[(nt * 16 + lr) * KP + kc * 32 + lg * 8]);

  const int gw = (gb >> 1) * 4 + (t >> 6);
  const int nw = ((gridDim.x - fillB) >> 1) * 4;
  const int mtiles = (n + 15) / 16;

  for (int mt = gw; mt < mtiles; mt += nw) {
    const int row  = mt * 16 + lr;
    const int crow = (row < n) ? row : (n - 1);

    bf16x8 afrag[KC];
#pragma unroll
    for (int kc = 0; kc < KC; ++kc) {
      const f32x4* p = reinterpret_cast<const f32x4*>(
          X + (size_t)crow * K + kc * 32 + lg * 8);
      f32x4 v0 = p[0], v1 = p[1];
      bf16x8 a;
      a[0] = (__bf16)v0[0]; a[1] = (__bf16)v0[1];
      a[2] = (__bf16)v0[2]; a[3] = (__bf16)v0[3];
      a[4] = (__bf16)v1[0]; a[5] = (__bf16)v1[1];
      a[6] = (__bf16)v1[2]; a[7] = (__bf16)v1[3];
      afrag[kc] = a;
    }

    f32x4 acc[NT];
#pragma unroll
    for (int nt = 0; nt < NT; ++nt) acc[nt] = (f32x4){0.f, 0.f, 0.f, 0.f};
#pragma unroll
    for (int kc = 0; kc < KC; ++kc)
#pragma unroll
      for (int nt = 0; nt < NT; ++nt)
        acc[nt] = __builtin_amdgcn_mfma_f32_16x16x32_bf16(afrag[kc], bfrag[nt][kc],
                                                          acc[nt], 0, 0, 0);

#pragma unroll
    for (int nt = 0; nt < NT; ++nt)
#pragma unroll
      for (int r = 0; r < 4; ++r) {
        int orow = mt * 16 + lg * 4 + r;
        if (orow < n)
          C[(size_t)orow * NC + ch * 64 + nt * 16 + lr] = (__bf16)acc[nt][r];
      }
  }
}

// ---------------- kernel 3: bins -> padded CSR + cnt/dinv + h1b*=dinv (SUBS=2) ----------------

__global__ __launch_bounds__(512) void csr_build_k(const int* __restrict__ bincur,
                                                   const u64* __restrict__ bin_data,
                                                   int* __restrict__ srcs_pad,
                                                   int* __restrict__ cnt,
                                                   float* __restrict__ dinv,
                                                   __bf16* __restrict__ h1b, int n) {
  __shared__ int rows[NPS * STR];   // 34816 B
  __shared__ int lcnt[NPS];

  const int bin = blockIdx.x / SUBS;
  const int sub = blockIdx.x % SUBS;
  const int lo  = (bin << BIN_SHIFT) + sub * NPS;
  const int hi  = min(n, lo + NPS);

  for (int i = threadIdx.x; i < NPS * STR; i += 512) rows[i] = n;  // sentinel
  for (int i = threadIdx.x; i < NPS; i += 512) lcnt[i] = 0;
  __syncthreads();

  int cntE = bincur[bin * CUR_STR];
  cntE = cntE < CAP ? cntE : CAP;
  const u64* bd = bin_data + (size_t)bin * CAP;

  for (int i = threadIdx.x; i < cntE; i += 512) {
    u64 p = bd[i];
    int d = (int)(p & 0xffffffffu);
    unsigned l = (unsigned)(d - lo);
    if (l < (unsigned)NPS) {
      int q = atomicAdd(&lcnt[l], 1);
      if (q < PAD) rows[l * STR + q] = (int)(p >> 32);
    }
  }
  __syncthreads();

  for (int i = threadIdx.x; i < NPS * (PAD / 4); i += 512) {
    int nl = i >> 4;
    int c4 = i & 15;
    int g = lo + nl;
    if (g < hi)
      *reinterpret_cast<int4*>(&srcs_pad[(size_t)g * PAD + c4 * 4]) =
          *reinterpret_cast<const int4*>(&rows[nl * STR + c4 * 4]);
  }
  for (int i = threadIdx.x; i < NPS; i += 512) {
    int g = lo + i;
    if (g < hi) {
      int c = lcnt[i];
      cnt[g] = c;
      dinv[g] = rsqrtf((float)(c + 1));
    }
  }
  bf16x8* h8 = reinterpret_cast<bf16x8*>(h1b);
  for (int i = threadIdx.x; i < NPS * 16; i += 512) {
    int nl = i >> 4;
    int c8 = i & 15;
    int g = lo + nl;
    if (g < hi) {
      float di = rsqrtf((float)(lcnt[nl] + 1));
      bf16x8 v = h8[(size_t)g * 16 + c8];
      bf16x8 o;
#pragma unroll
      for (int q = 0; q < 8; ++q) o[q] = (__bf16)((float)v[q] * di);
      h8[(size_t)g * 16 + c8] = o;
    }
  }
}

// ---------------- kernel 4: fused {gather1 -> LDS -> GEMM2 -> scaled h3b}, 32 nodes ----------------

__global__ __launch_bounds__(256) void gather_gemm2_k(
    const __bf16* __restrict__ h1b, const int* __restrict__ cnt,
    const int* __restrict__ srcs_pad, const float* __restrict__ dinv,
    const float* __restrict__ b1, const float* __restrict__ W2,
    __bf16* __restrict__ h3b, int n) {
  constexpr int K  = 128;
  constexpr int KP = 136;
  constexpr int KC = 4;

  __shared__ __bf16 W2T[64 * KP];    // 17408 B
  __shared__ __bf16 aggT[GGN * KP];  // 8704 B

  const int t = threadIdx.x;

  for (int idx = t; idx < K * 64 / 4; idx += 256) {
    int col = idx & 63;
    int k4  = idx >> 6;
    bf16x4 w;
    w[0] = (__bf16)W2[(k4 * 4 + 0) * 64 + col];
    w[1] = (__bf16)W2[(k4 * 4 + 1) * 64 + col];
    w[2] = (__bf16)W2[(k4 * 4 + 2) * 64 + col];
    w[3] = (__bf16)W2[(k4 * 4 + 3) * 64 + col];
    *reinterpret_cast<bf16x4*>(&W2T[col * KP + k4 * 4]) = w;
  }

  const int base = blockIdx.x * GGN;
  const bf16x8* h8 = reinterpret_cast<const bf16x8*>(h1b);
#pragma unroll
  for (int pass = 0; pass < 2; ++pass) {
    const int nl = pass * 16 + (t >> 4);
    const int d8 = t & 15;
    const int node = base + nl;
    bf16x8 ov;
    if (node < n) {
      int c = cnt[node];
      c = c < PAD ? c : PAD;
      const float di = dinv[node];
      const int* row = srcs_pad + (size_t)node * PAD;
      bf16x8 sv = h8[(size_t)node * 16 + d8];

      float acc[8];
#pragma unroll
      for (int q = 0; q < 8; ++q) acc[q] = 0.f;

      for (int j0 = 0; j0 < c; j0 += 8) {
        int4 a = *reinterpret_cast<const int4*>(row + j0);
        int4 b = *reinterpret_cast<const int4*>(row + j0 + 4);
        bf16x8 v0 = h8[(size_t)a.x * 16 + d8];
        bf16x8 v1 = h8[(size_t)a.y * 16 + d8];
        bf16x8 v2 = h8[(size_t)a.z * 16 + d8];
        bf16x8 v3 = h8[(size_t)a.w * 16 + d8];
        bf16x8 v4 = h8[(size_t)b.x * 16 + d8];
        bf16x8 v5 = h8[(size_t)b.y * 16 + d8];
        bf16x8 v6 = h8[(size_t)b.z * 16 + d8];
        bf16x8 v7 = h8[(size_t)b.w * 16 + d8];
#pragma unroll
        for (int q = 0; q < 8; ++q)
          acc[q] += ((float)v0[q] + (float)v1[q]) + ((float)v2[q] + (float)v3[q]) +
                    ((float)v4[q] + (float)v5[q]) + ((float)v6[q] + (float)v7[q]);
      }
#pragma unroll
      for (int q = 0; q < 8; ++q) {
        float val = (acc[q] + (float)sv[q]) * di + b1[d8 * 8 + q];
        ov[q] = (__bf16)fmaxf(val, 0.f);
      }
    } else {
#pragma unroll
      for (int q = 0; q < 8; ++q) ov[q] = (__bf16)0.f;
    }
    *reinterpret_cast<bf16x8*>(&aggT[nl * KP + d8 * 8]) = ov;
  }
  __syncthreads();

  const int lane = t & 63;
  const int lr = lane & 15;
  const int lg = lane >> 4;
  const int wv = t >> 6;
  const int mrow = (wv & 1) * 16;
  const int ch   = wv >> 1;

  bf16x8 bfrag[2][KC];
#pragma unroll
  for (int nt = 0; nt < 2; ++nt)
#pragma unroll
    for (int kc = 0; kc < KC; ++kc)
      bfrag[nt][kc] = *reinterpret_cast<const bf16x8*>(
          &W2T[((ch * 2 + nt) * 16 + lr) * KP + kc * 32 + lg * 8]);

  bf16x8 afrag[KC];
#pragma unroll
  for (int kc = 0; kc < KC; ++kc)
    afrag[kc] = *reinterpret_cast<const bf16x8*>(
        &aggT[(mrow + lr) * KP + kc * 32 + lg * 8]);

  f32x4 acc[2];
#pragma unroll
  for (int nt = 0; nt < 2; ++nt) acc[nt] = (f32x4){0.f, 0.f, 0.f, 0.f};
#pragma unroll
  for (int kc = 0; kc < KC; ++kc)
#pragma unroll
    for (int nt = 0; nt < 2; ++nt)
      acc[nt] = __builtin_amdgcn_mfma_f32_16x16x32_bf16(afrag[kc], bfrag[nt][kc],
                                                        acc[nt], 0, 0, 0);

#pragma unroll
  for (int r = 0; r < 4; ++r) {
    int orow = base + mrow + lg * 4 + r;
    if (orow < n) {
      float sc = dinv[orow];
#pragma unroll
      for (int nt = 0; nt < 2; ++nt)
        h3b[(size_t)orow * 64 + (ch * 2 + nt) * 16 + lr] = (__bf16)(acc[nt][r] * sc);
    }
  }
}

// ---------------- kernel 5: gather2 (branchless 8-wide, sentinel zero row) ----------------

template<int D, bool RELU_OUT, bool OUT_BF16>
__global__ __launch_bounds__(256) void gather_bf_k(const __bf16* __restrict__ h,
                                                   const int* __restrict__ cnt,
                                                   const int* __restrict__ srcs_pad,
                                                   const float* __restrict__ dinv,
                                                   const float* __restrict__ bias,
                                                   void* __restrict__ outv, int n) {
  constexpr int L = D / 8;
  int t = blockIdx.x * 256 + threadIdx.x;
  int node = t / L;
  int d8 = t % L;
  if (node >= n) return;

  int c = cnt[node];
  c = c < PAD ? c : PAD;
  const float di = dinv[node];
  const int* row = srcs_pad + (size_t)node * PAD;
  const bf16x8* h8 = reinterpret_cast<const bf16x8*>(h);
  bf16x8 sv = h8[(size_t)node * L + d8];

  float acc[8];
#pragma unroll
  for (int q = 0; q < 8; ++q) acc[q] = 0.f;

  for (int j0 = 0; j0 < c; j0 += 8) {
    int4 a = *reinterpret_cast<const int4*>(row + j0);
    int4 b = *reinterpret_cast<const int4*>(row + j0 + 4);
    bf16x8 v0 = h8[(size_t)a.x * L + d8];
    bf16x8 v1 = h8[(size_t)a.y * L + d8];
    bf16x8 v2 = h8[(size_t)a.z * L + d8];
    bf16x8 v3 = h8[(size_t)a.w * L + d8];
    bf16x8 v4 = h8[(size_t)b.x * L + d8];
    bf16x8 v5 = h8[(size_t)b.y * L + d8];
    bf16x8 v6 = h8[(size_t)b.z * L + d8];
    bf16x8 v7 = h8[(size_t)b.w * L + d8];
#pragma unroll
    for (int q = 0; q < 8; ++q)
      acc[q] += ((float)v0[q] + (float)v1[q]) + ((float)v2[q] + (float)v3[q]) +
                ((float)v4[q] + (float)v5[q]) + ((float)v6[q] + (float)v7[q]);
  }

  float o[8];
#pragma unroll
  for (int q = 0; q < 8; ++q) {
    float b = bias[d8 * 8 + q];
    float val = (acc[q] + (float)sv[q]) * di + b;
    o[q] = RELU_OUT ? fmaxf(val, 0.f) : val;
  }

  if (OUT_BF16) {
    bf16x8 ov;
#pragma unroll
    for (int q = 0; q < 8; ++q) ov[q] = (__bf16)o[q];
    reinterpret_cast<bf16x8*>(outv)[(size_t)node * L + d8] = ov;
  } else {
    f32x4 lo = {o[0], o[1], o[2], o[3]};
    f32x4 hi = {o[4], o[5], o[6], o[7]};
    f32x4* op = reinterpret_cast<f32x4*>((float*)outv + (size_t)node * D + d8 * 8);
    op[0] = lo;
    op[1] = hi;
  }
}

// ---------------- launch ----------------

extern "C" void kernel_launch(void* const* d_in, const int* in_sizes, int n_in,
                              void* d_out, int out_size, void* d_ws, size_t ws_size,
                              hipStream_t stream) {
  const float* x  = (const float*)d_in[0];
  const int*   ei = (const int*)d_in[1];
  const float* W1 = (const float*)d_in[2];
  const float* b1 = (const float*)d_in[3];
  const float* W2 = (const float*)d_in[4];
  const float* b2 = (const float*)d_in[5];

  const int n = in_sizes[0] / 128;   // 50000
  const int E = in_sizes[1] / 2;     // 800000
  const int* src = ei;
  const int* dst = ei + E;
  float* out = (float*)d_out;

  const int NBIN = (n + ((1 << BIN_SHIFT) - 1)) >> BIN_SHIFT;  // 196

  // workspace (4B words):
  // bincur[NBMAX*CUR_STR] | cnt[n] | dinv[n] | srcs_pad[n*PAD]
  // | h1b[(n+1)*128 bf16] | scratch (bin_data aliases, 196*6144*8 = 9.6MB) | h3b[(n+1)*64 bf16]
  int*   bincur   = (int*)d_ws;
  int*   cnt      = (int*)d_ws + NBMAX * CUR_STR;
  float* dinv     = (float*)d_ws + NBMAX * CUR_STR + n;
  int*   srcs_pad = (int*)d_ws + NBMAX * CUR_STR + 2 * n;
  size_t w = (size_t)NBMAX * CUR_STR + 2 * n + (size_t)n * PAD;
  __bf16* h1b     = (__bf16*)((int*)d_ws + w);   w += (size_t)(n + 1) * 64;
  __bf16* scratch = (__bf16*)((int*)d_ws + w);   w += (size_t)n * 64;
  __bf16* h3b     = (__bf16*)((int*)d_ws + w);
  u64* bin_data = (u64*)scratch;

  init_k<<<1, 256, 0, stream>>>(bincur, h1b + (size_t)n * 128, h3b + (size_t)n * 64);

  // ---- role-split: minimal fill (196 blocks, 16 edges/thread) || 64-col GEMM1 (256 blocks) ----
  const int fillB = (E + EPB - 1) / EPB;      // 196
  const int gemmB = 256;
  fused_fill_gemm_k<<<fillB + gemmB, 256, 0, stream>>>(
      src, dst, bincur, bin_data, E, fillB, x, W1, h1b, n);

  // ---- padded CSR + cnt/dinv + pre-scale h1b (SUBS=2) ----
  csr_build_k<<<NBIN * SUBS, 512, 0, stream>>>(bincur, bin_data, srcs_pad, cnt, dinv, h1b, n);

  // ---- gather1 + GEMM2 fused -> h3b (scaled), 32 nodes/block ----
  gather_gemm2_k<<<(n + GGN - 1) / GGN, 256, 0, stream>>>(
      h1b, cnt, srcs_pad, dinv, b1, W2, h3b, n);

  // ---- gather2 -> out (fp32) ----
  {
    long long t = (long long)n * 8;
    gather_bf_k<64, false, false><<<(int)((t + 255) / 256), 256, 0, stream>>>(
        h3b, cnt, srcs_pad, dinv, b2, out, n);
  }
}